// Round 8
// baseline (217.799 us; speedup 1.0000x reference)
//
#include <hip/hip_runtime.h>
#include <hip/hip_bf16.h>
#include <stdint.h>

#define B_ 16
#define N_ 2048
#define D_ 128

typedef __bf16 bf16_t;
typedef bf16_t bf16x8 __attribute__((ext_vector_type(8)));
typedef float f32x4 __attribute__((ext_vector_type(4)));

// ---------------- K1: adj-pack (fused) + emb GEMM + fused q/k + exps ---------
__global__ __launch_bounds__(256, 2) void k_emb(const float* __restrict__ x,
                                                const float* __restrict__ W,
                                                const float* __restrict__ be,
                                                const float* __restrict__ wq,
                                                const float* __restrict__ bq,
                                                const float* __restrict__ wk,
                                                const float* __restrict__ bk,
                                                const float* __restrict__ adj,
                                                unsigned int* __restrict__ bits,
                                                bf16_t* __restrict__ Pb,
                                                float* __restrict__ qa, float* __restrict__ ka,
                                                float* __restrict__ Eq, float* __restrict__ eqs,
                                                float* __restrict__ Ek, float* __restrict__ eks) {
    __shared__ float xs[32][68];     // [k][n]  64n + pad
    __shared__ float ws[32][132];    // [k][d]  128d + pad
    __shared__ float qs[64], ks[64];
    int b  = blockIdx.y;
    int n0 = blockIdx.x * 64;
    int tid = threadIdx.x;
    int tx = tid & 15, ty = tid >> 4;   // tx: n-dir (4 n), ty: d-dir (8 d)
    if (tid < 64) { qs[tid] = 0.f; ks[tid] = 0.f; }

    // ---- fused adj pack: 512*256 threads, 32 elements each, coalesced ----
    {
        int base = (blockIdx.y * (N_ / 64) + blockIdx.x) * 256 + tid;
#pragma unroll 8
        for (int it = 0; it < (N_ * N_) / (512 * 256); ++it) {
            int t = base + it * (512 * 256);
            float v = adj[t];
            unsigned long long m = __ballot(v > 0.5f);
            if ((t & 63) == 0) {
                int i = t >> 11;
                int j = t & 2047;
                bits[i * 64 + (j >> 5)]     = (unsigned int)m;
                bits[i * 64 + (j >> 5) + 1] = (unsigned int)(m >> 32);
            }
        }
    }

    float acc[4][8] = {};               // [n][d]
    f32x4 xr[2], wr[4];

    auto loadregs = [&](int kc) {
#pragma unroll
        for (int s = 0; s < 2; ++s) {
            int p = tid + 256 * s;
            int n = p >> 3, kq = p & 7;
            xr[s] = *(const f32x4*)(x + ((size_t)(b * N_ + n0 + n)) * D_ + kc * 32 + kq * 4);
        }
#pragma unroll
        for (int s = 0; s < 4; ++s) {
            int p = tid + 256 * s;
            int d = p >> 3, kq = p & 7;
            wr[s] = *(const f32x4*)(W + (size_t)d * D_ + kc * 32 + kq * 4);
        }
    };
    auto writelds = [&]() {
#pragma unroll
        for (int s = 0; s < 2; ++s) {
            int p = tid + 256 * s;
            int n = p >> 3, kq = p & 7;
#pragma unroll
            for (int u = 0; u < 4; ++u) xs[kq * 4 + u][n] = xr[s][u];
        }
#pragma unroll
        for (int s = 0; s < 4; ++s) {
            int p = tid + 256 * s;
            int d = p >> 3, kq = p & 7;
#pragma unroll
            for (int u = 0; u < 4; ++u) ws[kq * 4 + u][d] = wr[s][u];
        }
    };

    loadregs(0);
    for (int kc = 0; kc < 4; ++kc) {
        writelds();
        __syncthreads();
        if (kc < 3) loadregs(kc + 1);
#pragma unroll 4
        for (int k = 0; k < 32; ++k) {
            f32x4 xv  = *(const f32x4*)&xs[k][tx * 4];
            f32x4 wv0 = *(const f32x4*)&ws[k][ty * 8];
            f32x4 wv1 = *(const f32x4*)&ws[k][ty * 8 + 4];
#pragma unroll
            for (int i = 0; i < 4; ++i)
#pragma unroll
                for (int j = 0; j < 8; ++j)
                    acc[i][j] += xv[i] * ((j < 4) ? wv0[j] : wv1[j - 4]);
        }
        __syncthreads();
    }

    float qp[4] = {}, kp[4] = {};
#pragma unroll
    for (int j = 0; j < 8; ++j) {
        int d = ty * 8 + j;
        float bj  = be[d];
        float wqj = wq[d];
        float wkj = wk[d];
        f32x4 o;
        bf16_t ob[4];
#pragma unroll
        for (int i = 0; i < 4; ++i) {
            o[i] = acc[i][j] + bj;
            qp[i] += o[i] * wqj;
            kp[i] += o[i] * wkj;
            ob[i] = (bf16_t)o[i];
        }
        *(uint2*)(Pb + ((size_t)b * D_ + d) * N_ + n0 + tx * 4) = *(uint2*)ob;
    }
#pragma unroll
    for (int i = 0; i < 4; ++i) {
        atomicAdd(&qs[tx * 4 + i], qp[i]);
        atomicAdd(&ks[tx * 4 + i], kp[i]);
    }
    __syncthreads();
    if (tid < 64) {
        int idx = b * N_ + n0 + tid;
        float aq = qs[tid] + bq[0];
        float ak = ks[tid] + bk[0];
        qa[idx] = aq;          ka[idx] = ak;
        Eq[idx] = expf(aq);    eqs[idx] = expf(0.01f * aq);
        Ek[idx] = expf(ak);    eks[idx] = expf(0.01f * ak);
    }
}

// ---------------- K2: denom + post, fused -----------------------------------
__global__ __launch_bounds__(1024) void k_denom(const unsigned int* __restrict__ bits,
                                                const float* __restrict__ qa,
                                                const float* __restrict__ ka,
                                                const float* __restrict__ Eq,
                                                const float* __restrict__ eqs,
                                                const float* __restrict__ Ek,
                                                const float* __restrict__ eks,
                                                float* __restrict__ rd,
                                                float* __restrict__ Eqr,
                                                float* __restrict__ eqr) {
    __shared__ float red[8][128];
    int jt  = blockIdx.x;     // 0..15
    int b   = blockIdx.y;     // 0..15
    int tid = threadIdx.x;
    int tj  = tid & 127;
    int sg  = tid >> 7;       // 0..7 (wave-uniform: sg = wave>>1)
    int j   = jt * 128 + tj;
    float qj  = qa[b * N_ + j];
    float Eqj = Eq[b * N_ + j];
    float eqj = eqs[b * N_ + j];
    int shift = j & 31;
    int wid   = j >> 5;
    float acc = 0.f;
    int i0 = sg * 256;
#pragma unroll 16
    for (int i = i0; i < i0 + 256; ++i) {
        float kk  = ka[b * N_ + i];
        float Ekk = Ek[b * N_ + i];
        float ekk = eks[b * N_ + i];
        unsigned int w = bits[i * 64 + wid];
        float z  = kk + qj;
        float f1 = z > 0.f ? Ekk : ekk;
        float f2 = z > 0.f ? Eqj : eqj;
        acc += ((w >> shift) & 1u) ? f1 * f2 : 1.0f;
    }
    red[sg][tj] = acc;
    __syncthreads();
    if (sg == 0) {
        float den = acc;
#pragma unroll
        for (int s = 1; s < 8; ++s) den += red[s][tj];
        float r = 1.0f / den;
        int idx = b * N_ + j;
        rd[idx]  = r;
        Eqr[idx] = Eqj * r;
        eqr[idx] = eqj * r;
    }
}

// ---------------- K3: vals = A' @ P ------------------------------------------
// A'[i,j] = edge ? (z>0?Ek_i:ek_i)*(z>0?Eqr_j:eqr_j) : rd_j   (5 VALU/elem)
// SELF-SUFFICIENT-WAVE restructure of the R4-proven kernel (same 64i x 128d
// tile, 64-j step, XCD decode, setprio). Each wave:
//   - generates ALL 4 A-frags it consumes (2 halves x 2 i-chunks) -> ldsA
//     exchange DELETED (VGPR is free: grid caps us at 2 blocks/CU, so up to
//     256 VGPR costs nothing; j-regs for both halves ~ +64 VGPR).
//   - stages its OWN d-half of the B-tile (8 g_load_lds; the dg-pair writes
//     identical bytes = benign same-value duplication) -> its own vmcnt
//     guarantees visibility of every LDS byte it reads -> NO barrier before
//     MFMA. ONE barrier/step remains (after lgkmcnt(0)) as ldsB reuse guard.
// vmcnt budget/step: 16 f32x4 + 2 uint2 masks + 8 stage = 26.
__global__ __launch_bounds__(256, 2) void k_attn(const float* __restrict__ qa,
                                                 const float* __restrict__ ka,
                                                 const float* __restrict__ Ek,
                                                 const float* __restrict__ eks,
                                                 const float* __restrict__ rd,
                                                 const float* __restrict__ Eqr,
                                                 const float* __restrict__ eqr,
                                                 const unsigned int* __restrict__ bits,
                                                 const bf16_t* __restrict__ Pb,
                                                 float* __restrict__ out) {
    __shared__ __align__(16) bf16_t ldsB[2][128 * 64];    // 32 KB, B dbuf only
    int n     = blockIdx.x;        // 0..511
    int xcd   = n & 7;             // HW round-robin: block n -> XCD n%8
    int slot  = n >> 3;            // 0..63 within this XCD
    int b     = xcd * 2 + (slot >> 5);   // XCD owns 2 batches
    int ibase = (slot & 31) * 64;        // walk i-tiles for fixed b
    int tid   = threadIdx.x;
    int w     = tid >> 6;          // 0..3
    int lane  = tid & 63;
    int m16   = lane & 15;
    int quad  = lane >> 4;
    int ig    = w & 1;             // i-group (32 i)
    int dg    = w >> 1;            // d-group (64 d)

    int iA = ibase + (2 * ig) * 16 + m16;
    int iB = iA + 16;
    float mkR0 = -ka[b * N_ + iA], mkR1 = -ka[b * N_ + iB];   // z>0 <=> q_j > -k_i
    float EkR0 = Ek[b * N_ + iA],  EkR1 = Ek[b * N_ + iB];
    float ekR0 = eks[b * N_ + iA], ekR1 = eks[b * N_ + iB];
    const unsigned int* brA = bits + (size_t)iA * 64;
    const unsigned int* brB = bits + (size_t)iB * 64;
    const float* qp  = qa  + b * N_;
    const float* Erp = Eqr + b * N_;
    const float* erp = eqr + b * N_;
    const float* rdp = rd  + b * N_;
    const bf16_t* PtB = Pb + (size_t)b * D_ * N_;

    f32x4 acc[2][4];   // [i-chunk][d-tile]
#pragma unroll
    for (int c = 0; c < 2; ++c)
#pragma unroll
        for (int nt = 0; nt < 4; ++nt) acc[c][nt] = (f32x4){0.f, 0.f, 0.f, 0.f};

    // ---- pipeline registers: BOTH halves now (parity x half x quad4) ----
    f32x4 qv4[2][2][2], Er4[2][2][2], er4[2][2][2], rd4[2][2][2];
    uint2 mAB[2][2];   // [par][row A/B]: .x = half0 word, .y = half1 word

    auto ldj = [&](int par, int jb) {
#pragma unroll
        for (int h = 0; h < 2; ++h) {
            int j0 = jb + h * 32 + quad * 8;
            qv4[par][h][0] = *(const f32x4*)(qp  + j0);
            qv4[par][h][1] = *(const f32x4*)(qp  + j0 + 4);
            Er4[par][h][0] = *(const f32x4*)(Erp + j0);
            Er4[par][h][1] = *(const f32x4*)(Erp + j0 + 4);
            er4[par][h][0] = *(const f32x4*)(erp + j0);
            er4[par][h][1] = *(const f32x4*)(erp + j0 + 4);
            rd4[par][h][0] = *(const f32x4*)(rdp + j0);
            rd4[par][h][1] = *(const f32x4*)(rdp + j0 + 4);
        }
        mAB[par][0] = *(const uint2*)&brA[jb >> 5];   // fused: exactly 1 dwordx2
        mAB[par][1] = *(const uint2*)&brB[jb >> 5];
    };

    // Stage OWN d-half (64 rows x 64 j, 8 KB) — 8 x g_load_lds, XOR swizzle
    // on the GLOBAL address. dg-pair waves duplicate (same bytes, benign).
    auto stage = [&](int bufi, int jb) {
#pragma unroll
        for (int t = 0; t < 8; ++t) {
            int d   = dg * 64 + t * 8 + (lane >> 3);     // row
            int g   = (lane & 7) ^ (d & 7);              // swizzled j-chunk
            const bf16_t* gp = PtB + (size_t)d * N_ + jb + g * 8;
            int off = dg * 8192 + t * 1024 + lane * 16;  // wave-uniform base + lane*16
            __builtin_amdgcn_global_load_lds(
                (const __attribute__((address_space(1))) void*)gp,
                (__attribute__((address_space(3))) void*)((char*)(&ldsB[bufi][0]) + off),
                16, 0, 0);
        }
    };

    // ---- A-gen: BOTH halves, both i-chunks, pure registers ----
    auto agen = [&](int par, bf16x8 (&af)[2][2]) {      // af[chunk][half]
#pragma unroll
        for (int h = 0; h < 2; ++h) {
            unsigned int mA = h ? mAB[par][0].y : mAB[par][0].x;
            unsigned int mB = h ? mAB[par][1].y : mAB[par][1].x;
#pragma unroll
            for (int t = 0; t < 8; ++t) {
                float qv = (t < 4) ? qv4[par][h][0][t] : qv4[par][h][1][t - 4];
                float Er = (t < 4) ? Er4[par][h][0][t] : Er4[par][h][1][t - 4];
                float er = (t < 4) ? er4[par][h][0][t] : er4[par][h][1][t - 4];
                float rj = (t < 4) ? rd4[par][h][0][t] : rd4[par][h][1][t - 4];
                int bit = quad * 8 + t;
                {
                    bool c = qv > mkR0;
                    float v = (c ? EkR0 : ekR0) * (c ? Er : er);
                    af[0][h][t] = (bf16_t)(((mA >> bit) & 1u) ? v : rj);
                }
                {
                    bool c = qv > mkR1;
                    float v = (c ? EkR1 : ekR1) * (c ? Er : er);
                    af[1][h][t] = (bf16_t)(((mB >> bit) & 1u) ? v : rj);
                }
            }
        }
    };

    // ---- MFMA: A from regs, B from self-staged ldsB ----
    auto mfma_phase = [&](int buf, bf16x8 (&af)[2][2]) {
#pragma unroll
        for (int h = 0; h < 2; ++h) {
            int cph = ((h * 4 + quad) ^ (m16 & 7)) * 8;
#pragma unroll
            for (int nt = 0; nt < 4; ++nt) {
                int d = dg * 64 + nt * 16 + m16;
                bf16x8 bf = *(const bf16x8*)&ldsB[buf][d * 64 + cph];
                acc[0][nt] = __builtin_amdgcn_mfma_f32_16x16x32_bf16(af[0][h], bf, acc[0][nt], 0, 0, 0);
                acc[1][nt] = __builtin_amdgcn_mfma_f32_16x16x32_bf16(af[1][h], bf, acc[1][nt], 0, 0, 0);
            }
        }
    };

    stage(0, 0);
    ldj(0, 0);
    int buf = 0;
#pragma unroll 1
    for (int s2 = 0; s2 < 15; ++s2) {          // steps 0..29
#pragma unroll
        for (int par = 0; par < 2; ++par) {
            int jb = (s2 * 2 + par) * 64;
            ldj(par ^ 1, jb + 64);             // j-side regs for next step
            stage(buf ^ 1, jb + 64);           // own-half B prefetch for next step

            bf16x8 af[2][2];
            agen(par, af);
            // drain everything up to LAST step's stage (this step's 26 stay
            // in flight); self-staged -> own vmcnt suffices, NO barrier here
            asm volatile("s_waitcnt vmcnt(26)" ::: "memory");

            __builtin_amdgcn_s_setprio(1);
            mfma_phase(buf, af);
            __builtin_amdgcn_s_setprio(0);

            asm volatile("s_waitcnt lgkmcnt(0)" ::: "memory");
            __builtin_amdgcn_s_barrier();      // single barrier: ldsB reuse guard
            buf ^= 1;
        }
    }
    {   // step 30: still prefetches step 31
        ldj(1, 31 * 64);
        stage(buf ^ 1, 31 * 64);
        bf16x8 af[2][2];
        agen(0, af);
        asm volatile("s_waitcnt vmcnt(26)" ::: "memory");
        __builtin_amdgcn_s_setprio(1);
        mfma_phase(buf, af);
        __builtin_amdgcn_s_setprio(0);
        asm volatile("s_waitcnt lgkmcnt(0)" ::: "memory");
        __builtin_amdgcn_s_barrier();
        buf ^= 1;
    }
    {   // step 31: nothing issued after -> full drain of own stage
        bf16x8 af[2][2];
        agen(1, af);
        asm volatile("s_waitcnt vmcnt(0)" ::: "memory");
        __builtin_amdgcn_s_setprio(1);
        mfma_phase(buf, af);
        __builtin_amdgcn_s_setprio(0);
    }

    // ---- epilogue: C layout col=lane&15 (d), row=quad*4+r (i) ----
#pragma unroll
    for (int c = 0; c < 2; ++c) {
        int irow = ibase + (2 * ig + c) * 16 + quad * 4;
#pragma unroll
        for (int nt = 0; nt < 4; ++nt) {
            int d = dg * 64 + nt * 16 + m16;
#pragma unroll
            for (int r = 0; r < 4; ++r)
                out[((size_t)b * N_ + irow + r) * D_ + d] = acc[c][nt][r];
        }
    }
}

extern "C" void kernel_launch(void* const* d_in, const int* in_sizes, int n_in,
                              void* d_out, int out_size, void* d_ws, size_t ws_size,
                              hipStream_t stream) {
    const float* x   = (const float*)d_in[0];
    const float* adj = (const float*)d_in[1];
    const float* W   = (const float*)d_in[2];
    const float* be  = (const float*)d_in[3];
    const float* wq  = (const float*)d_in[4];
    const float* bq  = (const float*)d_in[5];
    const float* wk  = (const float*)d_in[6];
    const float* bk  = (const float*)d_in[7];
    float* out = (float*)d_out;

    char* ws = (char*)d_ws;
    size_t off = 0;
    bf16_t* Pb = (bf16_t*)(ws + off); off += (size_t)B_ * D_ * N_ * 2;   // 8 MB
    float* qa  = (float*)(ws + off);  off += (size_t)B_ * N_ * 4;
    float* ka  = (float*)(ws + off);  off += (size_t)B_ * N_ * 4;
    float* Eq  = (float*)(ws + off);  off += (size_t)B_ * N_ * 4;
    float* eqs = (float*)(ws + off);  off += (size_t)B_ * N_ * 4;
    float* Ek  = (float*)(ws + off);  off += (size_t)B_ * N_ * 4;
    float* eks = (float*)(ws + off);  off += (size_t)B_ * N_ * 4;
    float* rd  = (float*)(ws + off);  off += (size_t)B_ * N_ * 4;
    float* Eqr = (float*)(ws + off);  off += (size_t)B_ * N_ * 4;
    float* eqr = (float*)(ws + off);  off += (size_t)B_ * N_ * 4;
    unsigned int* bits = (unsigned int*)(ws + off); off += (size_t)N_ * 64 * 4; // 512 KB

    k_emb<<<dim3(N_ / 64, B_), 256, 0, stream>>>(x, W, be, wq, bq, wk, bk,
                                                 adj, bits,
                                                 Pb, qa, ka, Eq, eqs, Ek, eks);
    k_denom<<<dim3(16, 16), 1024, 0, stream>>>(bits, qa, ka, Eq, eqs, Ek, eks,
                                               rd, Eqr, eqr);
    k_attn<<<512, 256, 0, stream>>>(qa, ka, Ek, eks, rd, Eqr, eqr,
                                    bits, Pb, out);
}

// Round 9
// 196.724 us; speedup vs baseline: 1.1071x; 1.1071x over previous
//
#include <hip/hip_runtime.h>
#include <hip/hip_bf16.h>
#include <stdint.h>

#define B_ 16
#define N_ 2048
#define D_ 128

typedef __bf16 bf16_t;
typedef bf16_t bf16x8 __attribute__((ext_vector_type(8)));
typedef float f32x4 __attribute__((ext_vector_type(4)));

// ---------------- K1: adj-pack (fused) + emb GEMM + fused q/k + exps ---------
__global__ __launch_bounds__(256, 2) void k_emb(const float* __restrict__ x,
                                                const float* __restrict__ W,
                                                const float* __restrict__ be,
                                                const float* __restrict__ wq,
                                                const float* __restrict__ bq,
                                                const float* __restrict__ wk,
                                                const float* __restrict__ bk,
                                                const float* __restrict__ adj,
                                                unsigned int* __restrict__ bits,
                                                bf16_t* __restrict__ Pb,
                                                float* __restrict__ qa, float* __restrict__ ka,
                                                float* __restrict__ Eq, float* __restrict__ eqs,
                                                float* __restrict__ Ek, float* __restrict__ eks) {
    __shared__ float xs[32][68];     // [k][n]  64n + pad
    __shared__ float ws[32][132];    // [k][d]  128d + pad
    __shared__ float qs[64], ks[64];
    int b  = blockIdx.y;
    int n0 = blockIdx.x * 64;
    int tid = threadIdx.x;
    int tx = tid & 15, ty = tid >> 4;   // tx: n-dir (4 n), ty: d-dir (8 d)
    if (tid < 64) { qs[tid] = 0.f; ks[tid] = 0.f; }

    // ---- fused adj pack: 512*256 threads, 32 elements each, coalesced ----
    {
        int base = (blockIdx.y * (N_ / 64) + blockIdx.x) * 256 + tid;
#pragma unroll 8
        for (int it = 0; it < (N_ * N_) / (512 * 256); ++it) {
            int t = base + it * (512 * 256);
            float v = adj[t];
            unsigned long long m = __ballot(v > 0.5f);
            if ((t & 63) == 0) {
                int i = t >> 11;
                int j = t & 2047;
                bits[i * 64 + (j >> 5)]     = (unsigned int)m;
                bits[i * 64 + (j >> 5) + 1] = (unsigned int)(m >> 32);
            }
        }
    }

    float acc[4][8] = {};               // [n][d]
    f32x4 xr[2], wr[4];

    auto loadregs = [&](int kc) {
#pragma unroll
        for (int s = 0; s < 2; ++s) {
            int p = tid + 256 * s;
            int n = p >> 3, kq = p & 7;
            xr[s] = *(const f32x4*)(x + ((size_t)(b * N_ + n0 + n)) * D_ + kc * 32 + kq * 4);
        }
#pragma unroll
        for (int s = 0; s < 4; ++s) {
            int p = tid + 256 * s;
            int d = p >> 3, kq = p & 7;
            wr[s] = *(const f32x4*)(W + (size_t)d * D_ + kc * 32 + kq * 4);
        }
    };
    auto writelds = [&]() {
#pragma unroll
        for (int s = 0; s < 2; ++s) {
            int p = tid + 256 * s;
            int n = p >> 3, kq = p & 7;
#pragma unroll
            for (int u = 0; u < 4; ++u) xs[kq * 4 + u][n] = xr[s][u];
        }
#pragma unroll
        for (int s = 0; s < 4; ++s) {
            int p = tid + 256 * s;
            int d = p >> 3, kq = p & 7;
#pragma unroll
            for (int u = 0; u < 4; ++u) ws[kq * 4 + u][d] = wr[s][u];
        }
    };

    loadregs(0);
    for (int kc = 0; kc < 4; ++kc) {
        writelds();
        __syncthreads();
        if (kc < 3) loadregs(kc + 1);
#pragma unroll 4
        for (int k = 0; k < 32; ++k) {
            f32x4 xv  = *(const f32x4*)&xs[k][tx * 4];
            f32x4 wv0 = *(const f32x4*)&ws[k][ty * 8];
            f32x4 wv1 = *(const f32x4*)&ws[k][ty * 8 + 4];
#pragma unroll
            for (int i = 0; i < 4; ++i)
#pragma unroll
                for (int j = 0; j < 8; ++j)
                    acc[i][j] += xv[i] * ((j < 4) ? wv0[j] : wv1[j - 4]);
        }
        __syncthreads();
    }

    float qp[4] = {}, kp[4] = {};
#pragma unroll
    for (int j = 0; j < 8; ++j) {
        int d = ty * 8 + j;
        float bj  = be[d];
        float wqj = wq[d];
        float wkj = wk[d];
        f32x4 o;
        bf16_t ob[4];
#pragma unroll
        for (int i = 0; i < 4; ++i) {
            o[i] = acc[i][j] + bj;
            qp[i] += o[i] * wqj;
            kp[i] += o[i] * wkj;
            ob[i] = (bf16_t)o[i];
        }
        *(uint2*)(Pb + ((size_t)b * D_ + d) * N_ + n0 + tx * 4) = *(uint2*)ob;
    }
#pragma unroll
    for (int i = 0; i < 4; ++i) {
        atomicAdd(&qs[tx * 4 + i], qp[i]);
        atomicAdd(&ks[tx * 4 + i], kp[i]);
    }
    __syncthreads();
    if (tid < 64) {
        int idx = b * N_ + n0 + tid;
        float aq = qs[tid] + bq[0];
        float ak = ks[tid] + bk[0];
        qa[idx] = aq;          ka[idx] = ak;
        Eq[idx] = expf(aq);    eqs[idx] = expf(0.01f * aq);
        Ek[idx] = expf(ak);    eks[idx] = expf(0.01f * ak);
    }
}

// ---------------- K2: denom + post, fused -----------------------------------
__global__ __launch_bounds__(1024) void k_denom(const unsigned int* __restrict__ bits,
                                                const float* __restrict__ qa,
                                                const float* __restrict__ ka,
                                                const float* __restrict__ Eq,
                                                const float* __restrict__ eqs,
                                                const float* __restrict__ Ek,
                                                const float* __restrict__ eks,
                                                float* __restrict__ rd,
                                                float* __restrict__ Eqr,
                                                float* __restrict__ eqr) {
    __shared__ float red[8][128];
    int jt  = blockIdx.x;     // 0..15
    int b   = blockIdx.y;     // 0..15
    int tid = threadIdx.x;
    int tj  = tid & 127;
    int sg  = tid >> 7;       // 0..7 (wave-uniform: sg = wave>>1)
    int j   = jt * 128 + tj;
    float qj  = qa[b * N_ + j];
    float Eqj = Eq[b * N_ + j];
    float eqj = eqs[b * N_ + j];
    int shift = j & 31;
    int wid   = j >> 5;
    float acc = 0.f;
    int i0 = sg * 256;
#pragma unroll 16
    for (int i = i0; i < i0 + 256; ++i) {
        float kk  = ka[b * N_ + i];
        float Ekk = Ek[b * N_ + i];
        float ekk = eks[b * N_ + i];
        unsigned int w = bits[i * 64 + wid];
        float z  = kk + qj;
        float f1 = z > 0.f ? Ekk : ekk;
        float f2 = z > 0.f ? Eqj : eqj;
        acc += ((w >> shift) & 1u) ? f1 * f2 : 1.0f;
    }
    red[sg][tj] = acc;
    __syncthreads();
    if (sg == 0) {
        float den = acc;
#pragma unroll
        for (int s = 1; s < 8; ++s) den += red[s][tj];
        float r = 1.0f / den;
        int idx = b * N_ + j;
        rd[idx]  = r;
        Eqr[idx] = Eqj * r;
        eqr[idx] = eqj * r;
    }
}

// ---------------- K3: vals = A' @ P ------------------------------------------
// A'[i,j] = edge ? (z>0?Ek_i:ek_i)*(z>0?Eqr_j:eqr_j) : rd_j   (5 VALU/elem)
// R4-proven work structure (64i x 128d, 64-j step, A-exchange, XCD decode,
// setprio) + SINGLE-BARRIER sync (model from R0/R1/R7/R8: dur = serial chain
// + n_barriers x ~400ns convergence; this removes one barrier/step with ZERO
// added work). Per step:
//   agen+publish ldsA[par] -> vmcnt(0)+lgkmcnt(0) -> s_barrier
//   -> issue ldj+stage(next) -> MFMA(ldsA[par], ldsB[buf])
// Safety: every wave drains its OWN stage loads pre-barrier => post-barrier
// all of ldsB[buf] is visible (cross-wave rule preserved). ldsA parity-
// double-buffered: step-s reads (post-bar-s) vs step-s+2 writes (pre-bar-s+2)
// separated by barrier s+1. ldsB[buf^1] writes (post-bar-s) vs its step-s-1
// reads separated by barrier s. LDS 48 KB (2 blocks/CU, grid-capped anyway).
__global__ __launch_bounds__(256, 2) void k_attn(const float* __restrict__ qa,
                                                 const float* __restrict__ ka,
                                                 const float* __restrict__ Ek,
                                                 const float* __restrict__ eks,
                                                 const float* __restrict__ rd,
                                                 const float* __restrict__ Eqr,
                                                 const float* __restrict__ eqr,
                                                 const unsigned int* __restrict__ bits,
                                                 const bf16_t* __restrict__ Pb,
                                                 float* __restrict__ out) {
    __shared__ __align__(16) bf16_t ldsB[2][128 * 64];        // 32 KB, B dbuf
    __shared__ __align__(16) bf16_t ldsA[2][4 * 2 * 64 * 8];  // 16 KB, A exch (parity)
    int n     = blockIdx.x;        // 0..511
    int xcd   = n & 7;             // HW round-robin: block n -> XCD n%8
    int slot  = n >> 3;            // 0..63 within this XCD
    int b     = xcd * 2 + (slot >> 5);   // XCD owns 2 batches
    int ibase = (slot & 31) * 64;        // walk i-tiles for fixed b
    int tid   = threadIdx.x;
    int w     = tid >> 6;          // 0..3
    int lane  = tid & 63;
    int m16   = lane & 15;
    int quad  = lane >> 4;
    int ig    = w & 1;             // i-group (32 i)
    int dg    = w >> 1;            // d-group (64 d); also my j-half hh

    int iA = ibase + (2 * ig) * 16 + m16;
    int iB = iA + 16;
    float mkR0 = -ka[b * N_ + iA], mkR1 = -ka[b * N_ + iB];   // z>0 <=> q_j > -k_i
    float EkR0 = Ek[b * N_ + iA],  EkR1 = Ek[b * N_ + iB];
    float ekR0 = eks[b * N_ + iA], ekR1 = eks[b * N_ + iB];
    const unsigned int* brA = bits + (size_t)iA * 64;
    const unsigned int* brB = bits + (size_t)iB * 64;
    const float* qp  = qa  + b * N_;
    const float* Erp = Eqr + b * N_;
    const float* erp = eqr + b * N_;
    const float* rdp = rd  + b * N_;
    const bf16_t* PtB = Pb + (size_t)b * D_ * N_;

    f32x4 acc[2][4];   // [i-chunk][d-tile]
#pragma unroll
    for (int c = 0; c < 2; ++c)
#pragma unroll
        for (int nt = 0; nt < 4; ++nt) acc[c][nt] = (f32x4){0.f, 0.f, 0.f, 0.f};

    // ---- pipeline registers (parity-indexed; compile-time after unroll) ----
    f32x4 qv4[2][2], Er4[2][2], er4[2][2], rd4[2][2];  // [par][half4] (own hh only)
    unsigned int mA[2], mB[2];

    auto ldj = [&](int par, int jb) {
        int j0 = jb + dg * 32 + quad * 8;
        qv4[par][0] = *(const f32x4*)(qp  + j0);
        qv4[par][1] = *(const f32x4*)(qp  + j0 + 4);
        Er4[par][0] = *(const f32x4*)(Erp + j0);
        Er4[par][1] = *(const f32x4*)(Erp + j0 + 4);
        er4[par][0] = *(const f32x4*)(erp + j0);
        er4[par][1] = *(const f32x4*)(erp + j0 + 4);
        rd4[par][0] = *(const f32x4*)(rdp + j0);
        rd4[par][1] = *(const f32x4*)(rdp + j0 + 4);
        mA[par] = brA[(jb >> 5) + dg];
        mB[par] = brB[(jb >> 5) + dg];
    };

    // Stage 128d x 64j bf16 tile (16 KB), XOR swizzle on the GLOBAL address.
    auto stage = [&](int bufi, int jb) {
#pragma unroll
        for (int t = 0; t < 4; ++t) {
            int off = t * 4096 + tid * 16;               // byte offset in tile
            int d   = off >> 7;                          // row (128 B = 64 j)
            int g   = ((off & 127) >> 4) ^ (d & 7);      // swizzled j-chunk
            const bf16_t* gp = PtB + (size_t)d * N_ + jb + g * 8;
            __builtin_amdgcn_global_load_lds(
                (const __attribute__((address_space(1))) void*)gp,
                (__attribute__((address_space(3))) void*)((char*)(&ldsB[bufi][0]) + off),
                16, 0, 0);
        }
    };

    // ---- A-gen: own hh only, both i-chunks, from registers; publish ldsA[par]
    auto agen = [&](int par, bf16x8& afA, bf16x8& afB) {
#pragma unroll
        for (int t = 0; t < 8; ++t) {
            float qv = (t < 4) ? qv4[par][0][t] : qv4[par][1][t - 4];
            float Er = (t < 4) ? Er4[par][0][t] : Er4[par][1][t - 4];
            float er = (t < 4) ? er4[par][0][t] : er4[par][1][t - 4];
            float rj = (t < 4) ? rd4[par][0][t] : rd4[par][1][t - 4];
            int bit = quad * 8 + t;
            {
                bool c = qv > mkR0;
                float v = (c ? EkR0 : ekR0) * (c ? Er : er);
                afA[t] = (bf16_t)(((mA[par] >> bit) & 1u) ? v : rj);
            }
            {
                bool c = qv > mkR1;
                float v = (c ? EkR1 : ekR1) * (c ? Er : er);
                afB[t] = (bf16_t)(((mB[par] >> bit) & 1u) ? v : rj);
            }
        }
        *(bf16x8*)((char*)&ldsA[par][0] + ((((2 * ig + 0) * 2 + dg) * 64 + lane) * 16)) = afA;
        *(bf16x8*)((char*)&ldsA[par][0] + ((((2 * ig + 1) * 2 + dg) * 64 + lane) * 16)) = afB;
    };

    // ---- MFMA: own hh from regs, other hh from ldsA[par] ----
    auto mfma_phase = [&](int buf, int par, const bf16x8& afA, const bf16x8& afB) {
        {
            int cph = ((dg * 4 + quad) ^ (m16 & 7)) * 8;
#pragma unroll
            for (int nt = 0; nt < 4; ++nt) {
                int d = dg * 64 + nt * 16 + m16;
                bf16x8 bf = *(const bf16x8*)&ldsB[buf][d * 64 + cph];
                acc[0][nt] = __builtin_amdgcn_mfma_f32_16x16x32_bf16(afA, bf, acc[0][nt], 0, 0, 0);
                acc[1][nt] = __builtin_amdgcn_mfma_f32_16x16x32_bf16(afB, bf, acc[1][nt], 0, 0, 0);
            }
        }
        {
            int oh = 1 - dg;
            bf16x8 a0 = *(const bf16x8*)((char*)&ldsA[par][0] + ((((2 * ig + 0) * 2 + oh) * 64 + lane) * 16));
            bf16x8 a1 = *(const bf16x8*)((char*)&ldsA[par][0] + ((((2 * ig + 1) * 2 + oh) * 64 + lane) * 16));
            int cph = ((oh * 4 + quad) ^ (m16 & 7)) * 8;
#pragma unroll
            for (int nt = 0; nt < 4; ++nt) {
                int d = dg * 64 + nt * 16 + m16;
                bf16x8 bf = *(const bf16x8*)&ldsB[buf][d * 64 + cph];
                acc[0][nt] = __builtin_amdgcn_mfma_f32_16x16x32_bf16(a0, bf, acc[0][nt], 0, 0, 0);
                acc[1][nt] = __builtin_amdgcn_mfma_f32_16x16x32_bf16(a1, bf, acc[1][nt], 0, 0, 0);
            }
        }
    };

    stage(0, 0);
    ldj(0, 0);
    int buf = 0;
#pragma unroll 1
    for (int s2 = 0; s2 < 15; ++s2) {          // steps 0..29
#pragma unroll
        for (int par = 0; par < 2; ++par) {
            int jb = (s2 * 2 + par) * 64;

            bf16x8 afA, afB;
            agen(par, afA, afB);
            // drain OWN remaining loads (prev step's 4 stage) + publish, then
            // the ONE barrier: after it, everyone's ldsB[buf] stage + ldsA[par]
            // publish are visible.
            asm volatile("s_waitcnt vmcnt(0) lgkmcnt(0)" ::: "memory");
            __builtin_amdgcn_s_barrier();

            ldj(par ^ 1, jb + 64);             // next step's j-regs
            stage(buf ^ 1, jb + 64);           // next step's B prefetch

            __builtin_amdgcn_s_setprio(1);
            mfma_phase(buf, par, afA, afB);
            __builtin_amdgcn_s_setprio(0);
            buf ^= 1;
        }
    }
    {   // step 30: still prefetches step 31
        bf16x8 afA, afB;
        agen(0, afA, afB);
        asm volatile("s_waitcnt vmcnt(0) lgkmcnt(0)" ::: "memory");
        __builtin_amdgcn_s_barrier();
        ldj(1, 31 * 64);
        stage(buf ^ 1, 31 * 64);
        __builtin_amdgcn_s_setprio(1);
        mfma_phase(buf, 0, afA, afB);
        __builtin_amdgcn_s_setprio(0);
        buf ^= 1;
    }
    {   // step 31: nothing issued after the barrier
        bf16x8 afA, afB;
        agen(1, afA, afB);
        asm volatile("s_waitcnt vmcnt(0) lgkmcnt(0)" ::: "memory");
        __builtin_amdgcn_s_barrier();
        __builtin_amdgcn_s_setprio(1);
        mfma_phase(buf, 1, afA, afB);
        __builtin_amdgcn_s_setprio(0);
    }

    // ---- epilogue: C layout col=lane&15 (d), row=quad*4+r (i) ----
#pragma unroll
    for (int c = 0; c < 2; ++c) {
        int irow = ibase + (2 * ig + c) * 16 + quad * 4;
#pragma unroll
        for (int nt = 0; nt < 4; ++nt) {
            int d = dg * 64 + nt * 16 + m16;
#pragma unroll
            for (int r = 0; r < 4; ++r)
                out[((size_t)b * N_ + irow + r) * D_ + d] = acc[c][nt][r];
        }
    }
}

extern "C" void kernel_launch(void* const* d_in, const int* in_sizes, int n_in,
                              void* d_out, int out_size, void* d_ws, size_t ws_size,
                              hipStream_t stream) {
    const float* x   = (const float*)d_in[0];
    const float* adj = (const float*)d_in[1];
    const float* W   = (const float*)d_in[2];
    const float* be  = (const float*)d_in[3];
    const float* wq  = (const float*)d_in[4];
    const float* bq  = (const float*)d_in[5];
    const float* wk  = (const float*)d_in[6];
    const float* bk  = (const float*)d_in[7];
    float* out = (float*)d_out;

    char* ws = (char*)d_ws;
    size_t off = 0;
    bf16_t* Pb = (bf16_t*)(ws + off); off += (size_t)B_ * D_ * N_ * 2;   // 8 MB
    float* qa  = (float*)(ws + off);  off += (size_t)B_ * N_ * 4;
    float* ka  = (float*)(ws + off);  off += (size_t)B_ * N_ * 4;
    float* Eq  = (float*)(ws + off);  off += (size_t)B_ * N_ * 4;
    float* eqs = (float*)(ws + off);  off += (size_t)B_ * N_ * 4;
    float* Ek  = (float*)(ws + off);  off += (size_t)B_ * N_ * 4;
    float* eks = (float*)(ws + off);  off += (size_t)B_ * N_ * 4;
    float* rd  = (float*)(ws + off);  off += (size_t)B_ * N_ * 4;
    float* Eqr = (float*)(ws + off);  off += (size_t)B_ * N_ * 4;
    float* eqr = (float*)(ws + off);  off += (size_t)B_ * N_ * 4;
    unsigned int* bits = (unsigned int*)(ws + off); off += (size_t)N_ * 64 * 4; // 512 KB

    k_emb<<<dim3(N_ / 64, B_), 256, 0, stream>>>(x, W, be, wq, bq, wk, bk,
                                                 adj, bits,
                                                 Pb, qa, ka, Eq, eqs, Ek, eks);
    k_denom<<<dim3(16, 16), 1024, 0, stream>>>(bits, qa, ka, Eq, eqs, Ek, eks,
                                               rd, Eqr, eqr);
    k_attn<<<512, 256, 0, stream>>>(qa, ka, Ek, eks, rd, Eqr, eqr,
                                    bits, Pb, out);
}

// Round 10
// 193.461 us; speedup vs baseline: 1.1258x; 1.0169x over previous
//
#include <hip/hip_runtime.h>
#include <hip/hip_bf16.h>
#include <stdint.h>

#define B_ 16
#define N_ 2048
#define D_ 128

typedef __bf16 bf16_t;
typedef bf16_t bf16x8 __attribute__((ext_vector_type(8)));
typedef float f32x4 __attribute__((ext_vector_type(4)));

// ---------------- K1: adj-pack (fused) + emb GEMM + fused q/k + exps ---------
__global__ __launch_bounds__(256, 2) void k_emb(const float* __restrict__ x,
                                                const float* __restrict__ W,
                                                const float* __restrict__ be,
                                                const float* __restrict__ wq,
                                                const float* __restrict__ bq,
                                                const float* __restrict__ wk,
                                                const float* __restrict__ bk,
                                                const float* __restrict__ adj,
                                                unsigned int* __restrict__ bits,
                                                bf16_t* __restrict__ Pb,
                                                float* __restrict__ qa, float* __restrict__ ka,
                                                float* __restrict__ Eq, float* __restrict__ eqs,
                                                float* __restrict__ Ek, float* __restrict__ eks) {
    __shared__ float xs[32][68];     // [k][n]  64n + pad
    __shared__ float ws[32][132];    // [k][d]  128d + pad
    __shared__ float qs[64], ks[64];
    int b  = blockIdx.y;
    int n0 = blockIdx.x * 64;
    int tid = threadIdx.x;
    int tx = tid & 15, ty = tid >> 4;   // tx: n-dir (4 n), ty: d-dir (8 d)
    if (tid < 64) { qs[tid] = 0.f; ks[tid] = 0.f; }

    // ---- fused adj pack: 512*256 threads, 32 elements each, coalesced ----
    {
        int base = (blockIdx.y * (N_ / 64) + blockIdx.x) * 256 + tid;
#pragma unroll 8
        for (int it = 0; it < (N_ * N_) / (512 * 256); ++it) {
            int t = base + it * (512 * 256);
            float v = adj[t];
            unsigned long long m = __ballot(v > 0.5f);
            if ((t & 63) == 0) {
                int i = t >> 11;
                int j = t & 2047;
                bits[i * 64 + (j >> 5)]     = (unsigned int)m;
                bits[i * 64 + (j >> 5) + 1] = (unsigned int)(m >> 32);
            }
        }
    }

    float acc[4][8] = {};               // [n][d]
    f32x4 xr[2], wr[4];

    auto loadregs = [&](int kc) {
#pragma unroll
        for (int s = 0; s < 2; ++s) {
            int p = tid + 256 * s;
            int n = p >> 3, kq = p & 7;
            xr[s] = *(const f32x4*)(x + ((size_t)(b * N_ + n0 + n)) * D_ + kc * 32 + kq * 4);
        }
#pragma unroll
        for (int s = 0; s < 4; ++s) {
            int p = tid + 256 * s;
            int d = p >> 3, kq = p & 7;
            wr[s] = *(const f32x4*)(W + (size_t)d * D_ + kc * 32 + kq * 4);
        }
    };
    auto writelds = [&]() {
#pragma unroll
        for (int s = 0; s < 2; ++s) {
            int p = tid + 256 * s;
            int n = p >> 3, kq = p & 7;
#pragma unroll
            for (int u = 0; u < 4; ++u) xs[kq * 4 + u][n] = xr[s][u];
        }
#pragma unroll
        for (int s = 0; s < 4; ++s) {
            int p = tid + 256 * s;
            int d = p >> 3, kq = p & 7;
#pragma unroll
            for (int u = 0; u < 4; ++u) ws[kq * 4 + u][d] = wr[s][u];
        }
    };

    loadregs(0);
    for (int kc = 0; kc < 4; ++kc) {
        writelds();
        __syncthreads();
        if (kc < 3) loadregs(kc + 1);
#pragma unroll 4
        for (int k = 0; k < 32; ++k) {
            f32x4 xv  = *(const f32x4*)&xs[k][tx * 4];
            f32x4 wv0 = *(const f32x4*)&ws[k][ty * 8];
            f32x4 wv1 = *(const f32x4*)&ws[k][ty * 8 + 4];
#pragma unroll
            for (int i = 0; i < 4; ++i)
#pragma unroll
                for (int j = 0; j < 8; ++j)
                    acc[i][j] += xv[i] * ((j < 4) ? wv0[j] : wv1[j - 4]);
        }
        __syncthreads();
    }

    float qp[4] = {}, kp[4] = {};
#pragma unroll
    for (int j = 0; j < 8; ++j) {
        int d = ty * 8 + j;
        float bj  = be[d];
        float wqj = wq[d];
        float wkj = wk[d];
        f32x4 o;
        bf16_t ob[4];
#pragma unroll
        for (int i = 0; i < 4; ++i) {
            o[i] = acc[i][j] + bj;
            qp[i] += o[i] * wqj;
            kp[i] += o[i] * wkj;
            ob[i] = (bf16_t)o[i];
        }
        *(uint2*)(Pb + ((size_t)b * D_ + d) * N_ + n0 + tx * 4) = *(uint2*)ob;
    }
#pragma unroll
    for (int i = 0; i < 4; ++i) {
        atomicAdd(&qs[tx * 4 + i], qp[i]);
        atomicAdd(&ks[tx * 4 + i], kp[i]);
    }
    __syncthreads();
    if (tid < 64) {
        int idx = b * N_ + n0 + tid;
        float aq = qs[tid] + bq[0];
        float ak = ks[tid] + bk[0];
        qa[idx] = aq;          ka[idx] = ak;
        Eq[idx] = expf(aq);    eqs[idx] = expf(0.01f * aq);
        Ek[idx] = expf(ak);    eks[idx] = expf(0.01f * ak);
    }
}

// ---------------- K2: denom + post, fused -----------------------------------
__global__ __launch_bounds__(1024) void k_denom(const unsigned int* __restrict__ bits,
                                                const float* __restrict__ qa,
                                                const float* __restrict__ ka,
                                                const float* __restrict__ Eq,
                                                const float* __restrict__ eqs,
                                                const float* __restrict__ Ek,
                                                const float* __restrict__ eks,
                                                float* __restrict__ rd,
                                                float* __restrict__ Eqr,
                                                float* __restrict__ eqr) {
    __shared__ float red[8][128];
    int jt  = blockIdx.x;     // 0..15
    int b   = blockIdx.y;     // 0..15
    int tid = threadIdx.x;
    int tj  = tid & 127;
    int sg  = tid >> 7;       // 0..7 (wave-uniform: sg = wave>>1)
    int j   = jt * 128 + tj;
    float qj  = qa[b * N_ + j];
    float Eqj = Eq[b * N_ + j];
    float eqj = eqs[b * N_ + j];
    int shift = j & 31;
    int wid   = j >> 5;
    float acc = 0.f;
    int i0 = sg * 256;
#pragma unroll 16
    for (int i = i0; i < i0 + 256; ++i) {
        float kk  = ka[b * N_ + i];
        float Ekk = Ek[b * N_ + i];
        float ekk = eks[b * N_ + i];
        unsigned int w = bits[i * 64 + wid];
        float z  = kk + qj;
        float f1 = z > 0.f ? Ekk : ekk;
        float f2 = z > 0.f ? Eqj : eqj;
        acc += ((w >> shift) & 1u) ? f1 * f2 : 1.0f;
    }
    red[sg][tj] = acc;
    __syncthreads();
    if (sg == 0) {
        float den = acc;
#pragma unroll
        for (int s = 1; s < 8; ++s) den += red[s][tj];
        float r = 1.0f / den;
        int idx = b * N_ + j;
        rd[idx]  = r;
        Eqr[idx] = Eqj * r;
        eqr[idx] = eqj * r;
    }
}

// ---------------- K3: vals = A' @ P ------------------------------------------
// A'[i,j] = edge ? (z>0?Ek_i:ek_i)*(z>0?Eqr_j:eqr_j) : rd_j   (5 VALU/elem)
// R4-PROVEN SYNC SKELETON (2 barriers/step, vmcnt(14), A-exchange, XCD
// decode, setprio) + AGEN SOFTWARE-PIPELINE: agen(s+1) runs DURING step s's
// MFMA phase (VALU and MFMA are separate pipes, m114); the pre-barrier
// section only publishes the already-computed af(s) (2 ds_writes). Zero
// added work, identical barrier count; removes agen's serial VALU chain
// from the bar2(s-1)->bar1(s) critical path.
//   vmcnt ledger unchanged: at bar1(s) outstanding = ldj(s+1)+stage(s+1)=14
//   -> vmcnt(14) drains stage(s) exactly as R4.
//   ldsA parity-doubled (publish(s+1) vs MFMA(s-1) reads: 2 barriers apart).
//   j-regs single-buffered now (consumed in the same step they're loaded).
__global__ __launch_bounds__(256, 2) void k_attn(const float* __restrict__ qa,
                                                 const float* __restrict__ ka,
                                                 const float* __restrict__ Ek,
                                                 const float* __restrict__ eks,
                                                 const float* __restrict__ rd,
                                                 const float* __restrict__ Eqr,
                                                 const float* __restrict__ eqr,
                                                 const unsigned int* __restrict__ bits,
                                                 const bf16_t* __restrict__ Pb,
                                                 float* __restrict__ out) {
    __shared__ __align__(16) bf16_t ldsB[2][128 * 64];        // 32 KB, B dbuf
    __shared__ __align__(16) bf16_t ldsA[2][4 * 2 * 64 * 8];  // 16 KB, A exch (parity)
    int n     = blockIdx.x;        // 0..511
    int xcd   = n & 7;             // HW round-robin: block n -> XCD n%8
    int slot  = n >> 3;            // 0..63 within this XCD
    int b     = xcd * 2 + (slot >> 5);   // XCD owns 2 batches
    int ibase = (slot & 31) * 64;        // walk i-tiles for fixed b
    int tid   = threadIdx.x;
    int w     = tid >> 6;          // 0..3
    int lane  = tid & 63;
    int m16   = lane & 15;
    int quad  = lane >> 4;
    int ig    = w & 1;             // i-group (32 i)
    int dg    = w >> 1;            // d-group (64 d); also my j-half hh

    int iA = ibase + (2 * ig) * 16 + m16;
    int iB = iA + 16;
    float mkR0 = -ka[b * N_ + iA], mkR1 = -ka[b * N_ + iB];   // z>0 <=> q_j > -k_i
    float EkR0 = Ek[b * N_ + iA],  EkR1 = Ek[b * N_ + iB];
    float ekR0 = eks[b * N_ + iA], ekR1 = eks[b * N_ + iB];
    const unsigned int* brA = bits + (size_t)iA * 64;
    const unsigned int* brB = bits + (size_t)iB * 64;
    const float* qp  = qa  + b * N_;
    const float* Erp = Eqr + b * N_;
    const float* erp = eqr + b * N_;
    const float* rdp = rd  + b * N_;
    const bf16_t* PtB = Pb + (size_t)b * D_ * N_;

    f32x4 acc[2][4];   // [i-chunk][d-tile]
#pragma unroll
    for (int c = 0; c < 2; ++c)
#pragma unroll
        for (int nt = 0; nt < 4; ++nt) acc[c][nt] = (f32x4){0.f, 0.f, 0.f, 0.f};

    // ---- j-side registers: SINGLE buffer (loaded and consumed same step) ----
    f32x4 qv4[2], Er4[2], er4[2], rd4[2];
    unsigned int mA, mB;

    auto ldj = [&](int jb) {
        int j0 = jb + dg * 32 + quad * 8;
        qv4[0] = *(const f32x4*)(qp  + j0);
        qv4[1] = *(const f32x4*)(qp  + j0 + 4);
        Er4[0] = *(const f32x4*)(Erp + j0);
        Er4[1] = *(const f32x4*)(Erp + j0 + 4);
        er4[0] = *(const f32x4*)(erp + j0);
        er4[1] = *(const f32x4*)(erp + j0 + 4);
        rd4[0] = *(const f32x4*)(rdp + j0);
        rd4[1] = *(const f32x4*)(rdp + j0 + 4);
        mA = brA[(jb >> 5) + dg];
        mB = brB[(jb >> 5) + dg];
    };

    // Stage 128d x 64j bf16 tile (16 KB), XOR swizzle on the GLOBAL address.
    auto stage = [&](int bufi, int jb) {
#pragma unroll
        for (int t = 0; t < 4; ++t) {
            int off = t * 4096 + tid * 16;               // byte offset in tile
            int d   = off >> 7;                          // row (128 B = 64 j)
            int g   = ((off & 127) >> 4) ^ (d & 7);      // swizzled j-chunk
            const bf16_t* gp = PtB + (size_t)d * N_ + jb + g * 8;
            __builtin_amdgcn_global_load_lds(
                (const __attribute__((address_space(1))) void*)gp,
                (__attribute__((address_space(3))) void*)((char*)(&ldsB[bufi][0]) + off),
                16, 0, 0);
        }
    };

    // ---- A-gen: own hh, both i-chunks, pure registers (no LDS) ----
    auto agen = [&](bf16x8& afA, bf16x8& afB) {
#pragma unroll
        for (int t = 0; t < 8; ++t) {
            float qv = (t < 4) ? qv4[0][t] : qv4[1][t - 4];
            float Er = (t < 4) ? Er4[0][t] : Er4[1][t - 4];
            float er = (t < 4) ? er4[0][t] : er4[1][t - 4];
            float rj = (t < 4) ? rd4[0][t] : rd4[1][t - 4];
            int bit = quad * 8 + t;
            {
                bool c = qv > mkR0;
                float v = (c ? EkR0 : ekR0) * (c ? Er : er);
                afA[t] = (bf16_t)(((mA >> bit) & 1u) ? v : rj);
            }
            {
                bool c = qv > mkR1;
                float v = (c ? EkR1 : ekR1) * (c ? Er : er);
                afB[t] = (bf16_t)(((mB >> bit) & 1u) ? v : rj);
            }
        }
    };

    auto publish = [&](int par, const bf16x8& afA, const bf16x8& afB) {
        *(bf16x8*)((char*)&ldsA[par][0] + ((((2 * ig + 0) * 2 + dg) * 64 + lane) * 16)) = afA;
        *(bf16x8*)((char*)&ldsA[par][0] + ((((2 * ig + 1) * 2 + dg) * 64 + lane) * 16)) = afB;
    };

    // ---- MFMA: own hh from regs, other hh from ldsA[par] ----
    auto mfma_phase = [&](int buf, int par, const bf16x8& afA, const bf16x8& afB) {
        {
            int cph = ((dg * 4 + quad) ^ (m16 & 7)) * 8;
#pragma unroll
            for (int nt = 0; nt < 4; ++nt) {
                int d = dg * 64 + nt * 16 + m16;
                bf16x8 bf = *(const bf16x8*)&ldsB[buf][d * 64 + cph];
                acc[0][nt] = __builtin_amdgcn_mfma_f32_16x16x32_bf16(afA, bf, acc[0][nt], 0, 0, 0);
                acc[1][nt] = __builtin_amdgcn_mfma_f32_16x16x32_bf16(afB, bf, acc[1][nt], 0, 0, 0);
            }
        }
        {
            int oh = 1 - dg;
            bf16x8 a0 = *(const bf16x8*)((char*)&ldsA[par][0] + ((((2 * ig + 0) * 2 + oh) * 64 + lane) * 16));
            bf16x8 a1 = *(const bf16x8*)((char*)&ldsA[par][0] + ((((2 * ig + 1) * 2 + oh) * 64 + lane) * 16));
            int cph = ((oh * 4 + quad) ^ (m16 & 7)) * 8;
#pragma unroll
            for (int nt = 0; nt < 4; ++nt) {
                int d = dg * 64 + nt * 16 + m16;
                bf16x8 bf = *(const bf16x8*)&ldsB[buf][d * 64 + cph];
                acc[0][nt] = __builtin_amdgcn_mfma_f32_16x16x32_bf16(a0, bf, acc[0][nt], 0, 0, 0);
                acc[1][nt] = __builtin_amdgcn_mfma_f32_16x16x32_bf16(a1, bf, acc[1][nt], 0, 0, 0);
            }
        }
    };

    // ---- prologue: load + agen step 0 (af held in regs, published in loop) --
    bf16x8 afA, afB;     // fragment for the CURRENT step (computed one step early)
    ldj(0);              // 10 vm
    stage(0, 0);         // 4 vm
    agen(afA, afB);      // compiler inserts the vmcnt wait for ldj regs
    int buf = 0;
#pragma unroll 1
    for (int s2 = 0; s2 < 15; ++s2) {          // steps 0..29
#pragma unroll
        for (int par = 0; par < 2; ++par) {
            int jb = (s2 * 2 + par) * 64;

            // ---- pre-barrier: publish af(s), issue next step's 14 loads ----
            publish(par, afA, afB);
            ldj(jb + 64);                      // 10 vm (next step's j-regs)
            stage(buf ^ 1, jb + 64);           // 4 vm (next step's B)
            // outstanding = 14 just-issued; drain stage(s) + publish
            asm volatile("s_waitcnt vmcnt(14) lgkmcnt(0)" ::: "memory");
            __builtin_amdgcn_s_barrier();

            // ---- post-barrier: MFMA(s) overlapped with agen(s+1) ----
            bf16x8 nA, nB;
            __builtin_amdgcn_s_setprio(1);
            mfma_phase(buf, par, afA, afB);
            __builtin_amdgcn_s_setprio(0);
            agen(nA, nB);                      // VALU pipe; MFMAs drain meanwhile
            afA = nA; afB = nB;

            asm volatile("s_waitcnt lgkmcnt(0)" ::: "memory");
            __builtin_amdgcn_s_barrier();
            buf ^= 1;
        }
    }
    {   // step 30: still prefetches step 31
        publish(0, afA, afB);
        ldj(31 * 64);
        stage(buf ^ 1, 31 * 64);
        asm volatile("s_waitcnt vmcnt(14) lgkmcnt(0)" ::: "memory");
        __builtin_amdgcn_s_barrier();
        bf16x8 nA, nB;
        __builtin_amdgcn_s_setprio(1);
        mfma_phase(buf, 0, afA, afB);
        __builtin_amdgcn_s_setprio(0);
        agen(nA, nB);
        afA = nA; afB = nB;
        asm volatile("s_waitcnt lgkmcnt(0)" ::: "memory");
        __builtin_amdgcn_s_barrier();
        buf ^= 1;
    }
    {   // step 31: nothing issued after -> full drain of remaining stage
        publish(1, afA, afB);
        asm volatile("s_waitcnt vmcnt(0) lgkmcnt(0)" ::: "memory");
        __builtin_amdgcn_s_barrier();
        __builtin_amdgcn_s_setprio(1);
        mfma_phase(buf, 1, afA, afB);
        __builtin_amdgcn_s_setprio(0);
    }

    // ---- epilogue: C layout col=lane&15 (d), row=quad*4+r (i) ----
#pragma unroll
    for (int c = 0; c < 2; ++c) {
        int irow = ibase + (2 * ig + c) * 16 + quad * 4;
#pragma unroll
        for (int nt = 0; nt < 4; ++nt) {
            int d = dg * 64 + nt * 16 + m16;
#pragma unroll
            for (int r = 0; r < 4; ++r)
                out[((size_t)b * N_ + irow + r) * D_ + d] = acc[c][nt][r];
        }
    }
}

extern "C" void kernel_launch(void* const* d_in, const int* in_sizes, int n_in,
                              void* d_out, int out_size, void* d_ws, size_t ws_size,
                              hipStream_t stream) {
    const float* x   = (const float*)d_in[0];
    const float* adj = (const float*)d_in[1];
    const float* W   = (const float*)d_in[2];
    const float* be  = (const float*)d_in[3];
    const float* wq  = (const float*)d_in[4];
    const float* bq  = (const float*)d_in[5];
    const float* wk  = (const float*)d_in[6];
    const float* bk  = (const float*)d_in[7];
    float* out = (float*)d_out;

    char* ws = (char*)d_ws;
    size_t off = 0;
    bf16_t* Pb = (bf16_t*)(ws + off); off += (size_t)B_ * D_ * N_ * 2;   // 8 MB
    float* qa  = (float*)(ws + off);  off += (size_t)B_ * N_ * 4;
    float* ka  = (float*)(ws + off);  off += (size_t)B_ * N_ * 4;
    float* Eq  = (float*)(ws + off);  off += (size_t)B_ * N_ * 4;
    float* eqs = (float*)(ws + off);  off += (size_t)B_ * N_ * 4;
    float* Ek  = (float*)(ws + off);  off += (size_t)B_ * N_ * 4;
    float* eks = (float*)(ws + off);  off += (size_t)B_ * N_ * 4;
    float* rd  = (float*)(ws + off);  off += (size_t)B_ * N_ * 4;
    float* Eqr = (float*)(ws + off);  off += (size_t)B_ * N_ * 4;
    float* eqr = (float*)(ws + off);  off += (size_t)B_ * N_ * 4;
    unsigned int* bits = (unsigned int*)(ws + off); off += (size_t)N_ * 64 * 4; // 512 KB

    k_emb<<<dim3(N_ / 64, B_), 256, 0, stream>>>(x, W, be, wq, bq, wk, bk,
                                                 adj, bits,
                                                 Pb, qa, ka, Eq, eqs, Ek, eks);
    k_denom<<<dim3(16, 16), 1024, 0, stream>>>(bits, qa, ka, Eq, eqs, Ek, eks,
                                               rd, Eqr, eqr);
    k_attn<<<512, 256, 0, stream>>>(qa, ka, Ek, eks, rd, Eqr, eqr,
                                    bits, Pb, out);
}

// Round 11
// 183.074 us; speedup vs baseline: 1.1897x; 1.0567x over previous
//
#include <hip/hip_runtime.h>
#include <hip/hip_bf16.h>
#include <stdint.h>

#define B_ 16
#define N_ 2048
#define D_ 128

typedef __bf16 bf16_t;
typedef bf16_t bf16x8 __attribute__((ext_vector_type(8)));
typedef float f32x4 __attribute__((ext_vector_type(4)));

// ---------------- K0: pack adj (fp32 0/1 matrix) into bitmask ----------------
__global__ __launch_bounds__(256) void k_pack_adj(const float* __restrict__ adj,
                                                  unsigned int* __restrict__ bits) {
    int t = blockIdx.x * 256 + threadIdx.x;       // over N*N
    float v = adj[t];
    unsigned long long m = __ballot(v > 0.5f);
    if ((t & 63) == 0) {
        int i = t >> 11;
        int j = t & 2047;
        bits[i * 64 + (j >> 5)]     = (unsigned int)m;
        bits[i * 64 + (j >> 5) + 1] = (unsigned int)(m >> 32);
    }
}

// ---------------- K1: emb GEMM (64n x 128d tile) + fused q/k + exps ----------
// Pb[b][d][n] = bf16( sum_k x[b][n][k]*W[d][k] + be[d] )   (raw seq_fts, bf16)
// Also zero-inits denom (replaces the memset dispatch).
__global__ __launch_bounds__(256, 2) void k_emb(const float* __restrict__ x,
                                                const float* __restrict__ W,
                                                const float* __restrict__ be,
                                                const float* __restrict__ wq,
                                                const float* __restrict__ bq,
                                                const float* __restrict__ wk,
                                                const float* __restrict__ bk,
                                                bf16_t* __restrict__ Pb,
                                                float* __restrict__ qa, float* __restrict__ ka,
                                                float* __restrict__ Eq, float* __restrict__ eqs,
                                                float* __restrict__ Ek, float* __restrict__ eks,
                                                float* __restrict__ denom) {
    __shared__ float xs[32][68];     // [k][n]  64n + pad
    __shared__ float ws[32][132];    // [k][d]  128d + pad
    __shared__ float qs[64], ks[64];
    int b  = blockIdx.y;
    int n0 = blockIdx.x * 64;
    int tid = threadIdx.x;
    int tx = tid & 15, ty = tid >> 4;   // tx: n-dir (4 n), ty: d-dir (8 d)
    if (tid < 64) { qs[tid] = 0.f; ks[tid] = 0.f; }

    float acc[4][8] = {};               // [n][d]
    f32x4 xr[2], wr[4];

    auto loadregs = [&](int kc) {
#pragma unroll
        for (int s = 0; s < 2; ++s) {
            int p = tid + 256 * s;
            int n = p >> 3, kq = p & 7;
            xr[s] = *(const f32x4*)(x + ((size_t)(b * N_ + n0 + n)) * D_ + kc * 32 + kq * 4);
        }
#pragma unroll
        for (int s = 0; s < 4; ++s) {
            int p = tid + 256 * s;
            int d = p >> 3, kq = p & 7;
            wr[s] = *(const f32x4*)(W + (size_t)d * D_ + kc * 32 + kq * 4);
        }
    };
    auto writelds = [&]() {
#pragma unroll
        for (int s = 0; s < 2; ++s) {
            int p = tid + 256 * s;
            int n = p >> 3, kq = p & 7;
#pragma unroll
            for (int u = 0; u < 4; ++u) xs[kq * 4 + u][n] = xr[s][u];
        }
#pragma unroll
        for (int s = 0; s < 4; ++s) {
            int p = tid + 256 * s;
            int d = p >> 3, kq = p & 7;
#pragma unroll
            for (int u = 0; u < 4; ++u) ws[kq * 4 + u][d] = wr[s][u];
        }
    };

    loadregs(0);
    for (int kc = 0; kc < 4; ++kc) {
        writelds();
        __syncthreads();
        if (kc < 3) loadregs(kc + 1);
#pragma unroll 4
        for (int k = 0; k < 32; ++k) {
            f32x4 xv  = *(const f32x4*)&xs[k][tx * 4];
            f32x4 wv0 = *(const f32x4*)&ws[k][ty * 8];
            f32x4 wv1 = *(const f32x4*)&ws[k][ty * 8 + 4];
#pragma unroll
            for (int i = 0; i < 4; ++i)
#pragma unroll
                for (int j = 0; j < 8; ++j)
                    acc[i][j] += xv[i] * ((j < 4) ? wv0[j] : wv1[j - 4]);
        }
        __syncthreads();
    }

    float qp[4] = {}, kp[4] = {};
#pragma unroll
    for (int j = 0; j < 8; ++j) {
        int d = ty * 8 + j;
        float bj  = be[d];
        float wqj = wq[d];
        float wkj = wk[d];
        f32x4 o;
        bf16_t ob[4];
#pragma unroll
        for (int i = 0; i < 4; ++i) {
            o[i] = acc[i][j] + bj;
            qp[i] += o[i] * wqj;
            kp[i] += o[i] * wkj;
            ob[i] = (bf16_t)o[i];
        }
        *(uint2*)(Pb + ((size_t)b * D_ + d) * N_ + n0 + tx * 4) = *(uint2*)ob;
    }
#pragma unroll
    for (int i = 0; i < 4; ++i) {
        atomicAdd(&qs[tx * 4 + i], qp[i]);
        atomicAdd(&ks[tx * 4 + i], kp[i]);
    }
    __syncthreads();
    if (tid < 64) {
        int idx = b * N_ + n0 + tid;
        float aq = qs[tid] + bq[0];
        float ak = ks[tid] + bk[0];
        qa[idx] = aq;          ka[idx] = ak;
        Eq[idx] = expf(aq);    eqs[idx] = expf(0.01f * aq);
        Ek[idx] = expf(ak);    eks[idx] = expf(0.01f * ak);
        denom[idx] = 0.f;      // replaces hipMemsetAsync (k_denom runs after)
    }
}

// ---------------- K2: denom[b][j] = sum_i V(b,i,j) ---------------------------
__global__ __launch_bounds__(256) void k_denom(const unsigned int* __restrict__ bits,
                                               const float* __restrict__ qa,
                                               const float* __restrict__ ka,
                                               const float* __restrict__ Eq,
                                               const float* __restrict__ eqs,
                                               const float* __restrict__ Ek,
                                               const float* __restrict__ eks,
                                               float* __restrict__ denom) {
    int jt  = blockIdx.x;     // 0..7
    int b   = blockIdx.y;     // 0..15
    int seg = blockIdx.z;     // 0..7
    int j = jt * 256 + threadIdx.x;
    float qj  = qa[b * N_ + j];
    float Eqj = Eq[b * N_ + j];
    float eqj = eqs[b * N_ + j];
    int shift = j & 31;
    int wid   = j >> 5;
    float acc = 0.f;
    int i0 = seg * 256;
#pragma unroll 16
    for (int i = i0; i < i0 + 256; ++i) {
        float kk  = ka[b * N_ + i];
        float Ekk = Ek[b * N_ + i];
        float ekk = eks[b * N_ + i];
        unsigned int w = bits[i * 64 + wid];
        float z  = kk + qj;
        float f1 = z > 0.f ? Ekk : ekk;
        float f2 = z > 0.f ? Eqj : eqj;
        float v  = f1 * f2;
        acc += ((w >> shift) & 1u) ? v : 1.0f;
    }
    atomicAdd(&denom[b * N_ + j], acc);
}

// ---------------- K2b: rd = 1/denom; Eqr = Eq*rd; eqr = eqs*rd ---------------
__global__ __launch_bounds__(256) void k_post(const float* __restrict__ denom,
                                              const float* __restrict__ Eq,
                                              const float* __restrict__ eqs,
                                              float* __restrict__ rd,
                                              float* __restrict__ Eqr,
                                              float* __restrict__ eqr) {
    int t = blockIdx.x * 256 + threadIdx.x;   // over B*N
    float r = 1.0f / denom[t];
    rd[t]  = r;
    Eqr[t] = Eq[t] * r;
    eqr[t] = eqs[t] * r;
}

// ---------------- K3: vals = A' @ P ------------------------------------------
// A'[i,j] = edge ? (z>0?Ek_i:ek_i)*(z>0?Eqr_j:eqr_j) : rd_j   (5 VALU/elem)
// SESSION-BEST CONFIGURATION (measured 45.5 us k_attn / 183.0 us total, R4):
// 64i x 128d tile, 64-j step, counted-vmcnt pipeline (vmcnt(14), lgkm-only
// barrier2), A-exchange via ldsA, XCD-AWARE DECODE (FETCH 35 -> 6.7 MB: the
// 32 i-blocks sharing one batch's 512 KB Pb panel land on ONE XCD L2 instead
// of scattering across 8), setprio(1) around MFMA.
// Verified local optimum: R1/R3 (more blocks), R5 (rcp fusion), R7 (BK=128),
// R8 (self-sufficient waves), R9 (single barrier), R10 (agen pipeline) all
// regressed 10-65%. Latency-bound at 2 lockstep blocks/CU; not HBM/MFMA
// roofline, but every structural neighbor measured worse.
__global__ __launch_bounds__(256, 2) void k_attn(const float* __restrict__ qa,
                                                 const float* __restrict__ ka,
                                                 const float* __restrict__ Ek,
                                                 const float* __restrict__ eks,
                                                 const float* __restrict__ rd,
                                                 const float* __restrict__ Eqr,
                                                 const float* __restrict__ eqr,
                                                 const unsigned int* __restrict__ bits,
                                                 const bf16_t* __restrict__ Pb,
                                                 float* __restrict__ out) {
    __shared__ __align__(16) bf16_t ldsB[2][128 * 64];    // 32 KB, B dbuf
    __shared__ __align__(16) bf16_t ldsA[4 * 2 * 64 * 8]; // 8 KB, A exchange
    int n     = blockIdx.x;        // 0..511
    int xcd   = n & 7;             // HW round-robin: block n -> XCD n%8
    int slot  = n >> 3;            // 0..63 within this XCD
    int b     = xcd * 2 + (slot >> 5);   // XCD owns 2 batches
    int ibase = (slot & 31) * 64;        // walk i-tiles for fixed b
    int tid   = threadIdx.x;
    int w     = tid >> 6;          // 0..3
    int lane  = tid & 63;
    int m16   = lane & 15;
    int quad  = lane >> 4;
    int ig    = w & 1;             // i-group (32 i)
    int dg    = w >> 1;            // d-group (64 d); also my j-half hh

    int iA = ibase + (2 * ig) * 16 + m16;
    int iB = iA + 16;
    float mkR0 = -ka[b * N_ + iA], mkR1 = -ka[b * N_ + iB];   // z>0 <=> q_j > -k_i
    float EkR0 = Ek[b * N_ + iA],  EkR1 = Ek[b * N_ + iB];
    float ekR0 = eks[b * N_ + iA], ekR1 = eks[b * N_ + iB];
    const unsigned int* brA = bits + (size_t)iA * 64;
    const unsigned int* brB = bits + (size_t)iB * 64;
    const float* qp  = qa  + b * N_;
    const float* Erp = Eqr + b * N_;
    const float* erp = eqr + b * N_;
    const float* rdp = rd  + b * N_;
    const bf16_t* PtB = Pb + (size_t)b * D_ * N_;

    f32x4 acc[2][4];   // [i-chunk][d-tile]
#pragma unroll
    for (int c = 0; c < 2; ++c)
#pragma unroll
        for (int nt = 0; nt < 4; ++nt) acc[c][nt] = (f32x4){0.f, 0.f, 0.f, 0.f};

    // ---- pipeline registers (parity-indexed; compile-time after unroll) ----
    f32x4 qv4[2][2], Er4[2][2], er4[2][2], rd4[2][2];  // [par][half4] (own hh only)
    unsigned int mA[2], mB[2];

    auto ldj = [&](int par, int jb) {
        int j0 = jb + dg * 32 + quad * 8;
        qv4[par][0] = *(const f32x4*)(qp  + j0);
        qv4[par][1] = *(const f32x4*)(qp  + j0 + 4);
        Er4[par][0] = *(const f32x4*)(Erp + j0);
        Er4[par][1] = *(const f32x4*)(Erp + j0 + 4);
        er4[par][0] = *(const f32x4*)(erp + j0);
        er4[par][1] = *(const f32x4*)(erp + j0 + 4);
        rd4[par][0] = *(const f32x4*)(rdp + j0);
        rd4[par][1] = *(const f32x4*)(rdp + j0 + 4);
        mA[par] = brA[(jb >> 5) + dg];
        mB[par] = brB[(jb >> 5) + dg];
    };

    // Stage 128d x 64j bf16 tile (16 KB), XOR swizzle on the GLOBAL address.
    auto stage = [&](int bufi, int jb) {
#pragma unroll
        for (int t = 0; t < 4; ++t) {
            int off = t * 4096 + tid * 16;               // byte offset in tile
            int d   = off >> 7;                          // row (128 B = 64 j)
            int g   = ((off & 127) >> 4) ^ (d & 7);      // swizzled j-chunk
            const bf16_t* gp = PtB + (size_t)d * N_ + jb + g * 8;
            __builtin_amdgcn_global_load_lds(
                (const __attribute__((address_space(1))) void*)gp,
                (__attribute__((address_space(3))) void*)((char*)(&ldsB[bufi][0]) + off),
                16, 0, 0);
        }
    };

    // ---- A-gen: own hh only, both i-chunks, from registers; publish to ldsA.
    auto agen = [&](int par, bf16x8& afA, bf16x8& afB) {
#pragma unroll
        for (int t = 0; t < 8; ++t) {
            float qv = (t < 4) ? qv4[par][0][t] : qv4[par][1][t - 4];
            float Er = (t < 4) ? Er4[par][0][t] : Er4[par][1][t - 4];
            float er = (t < 4) ? er4[par][0][t] : er4[par][1][t - 4];
            float rj = (t < 4) ? rd4[par][0][t] : rd4[par][1][t - 4];
            int bit = quad * 8 + t;
            {
                bool c = qv > mkR0;
                float v = (c ? EkR0 : ekR0) * (c ? Er : er);
                afA[t] = (bf16_t)(((mA[par] >> bit) & 1u) ? v : rj);
            }
            {
                bool c = qv > mkR1;
                float v = (c ? EkR1 : ekR1) * (c ? Er : er);
                afB[t] = (bf16_t)(((mB[par] >> bit) & 1u) ? v : rj);
            }
        }
        *(bf16x8*)((char*)ldsA + ((((2 * ig + 0) * 2 + dg) * 64 + lane) * 16)) = afA;
        *(bf16x8*)((char*)ldsA + ((((2 * ig + 1) * 2 + dg) * 64 + lane) * 16)) = afB;
    };

    // ---- MFMA: own hh from regs, other hh from ldsA ----
    auto mfma_phase = [&](int buf, const bf16x8& afA, const bf16x8& afB) {
        {
            int cph = ((dg * 4 + quad) ^ (m16 & 7)) * 8;
#pragma unroll
            for (int nt = 0; nt < 4; ++nt) {
                int d = dg * 64 + nt * 16 + m16;
                bf16x8 bf = *(const bf16x8*)&ldsB[buf][d * 64 + cph];
                acc[0][nt] = __builtin_amdgcn_mfma_f32_16x16x32_bf16(afA, bf, acc[0][nt], 0, 0, 0);
                acc[1][nt] = __builtin_amdgcn_mfma_f32_16x16x32_bf16(afB, bf, acc[1][nt], 0, 0, 0);
            }
        }
        {
            int oh = 1 - dg;
            bf16x8 a0 = *(const bf16x8*)((char*)ldsA + ((((2 * ig + 0) * 2 + oh) * 64 + lane) * 16));
            bf16x8 a1 = *(const bf16x8*)((char*)ldsA + ((((2 * ig + 1) * 2 + oh) * 64 + lane) * 16));
            int cph = ((oh * 4 + quad) ^ (m16 & 7)) * 8;
#pragma unroll
            for (int nt = 0; nt < 4; ++nt) {
                int d = dg * 64 + nt * 16 + m16;
                bf16x8 bf = *(const bf16x8*)&ldsB[buf][d * 64 + cph];
                acc[0][nt] = __builtin_amdgcn_mfma_f32_16x16x32_bf16(a0, bf, acc[0][nt], 0, 0, 0);
                acc[1][nt] = __builtin_amdgcn_mfma_f32_16x16x32_bf16(a1, bf, acc[1][nt], 0, 0, 0);
            }
        }
    };

    stage(0, 0);
    ldj(0, 0);
    // no startup drain: barrier1 of step 0 (vmcnt(14)) covers the initial stage
    int buf = 0;
#pragma unroll 1
    for (int s2 = 0; s2 < 15; ++s2) {          // steps 0..29
#pragma unroll
        for (int par = 0; par < 2; ++par) {
            int jb = (s2 * 2 + par) * 64;
            ldj(par ^ 1, jb + 64);             // j-side regs for next step
            stage(buf ^ 1, jb + 64);           // B prefetch for next step

            bf16x8 afA, afB;
            agen(par, afA, afB);
            // this step's 14 loads were issued one step ago; the 14 just
            // issued stay in flight across the barrier
            asm volatile("s_waitcnt vmcnt(14) lgkmcnt(0)" ::: "memory");
            __builtin_amdgcn_s_barrier();

            __builtin_amdgcn_s_setprio(1);
            mfma_phase(buf, afA, afB);
            __builtin_amdgcn_s_setprio(0);

            asm volatile("s_waitcnt lgkmcnt(0)" ::: "memory");
            __builtin_amdgcn_s_barrier();
            buf ^= 1;
        }
    }
    {   // step 30: still prefetches step 31
        ldj(1, 31 * 64);
        stage(buf ^ 1, 31 * 64);
        bf16x8 afA, afB;
        agen(0, afA, afB);
        asm volatile("s_waitcnt vmcnt(14) lgkmcnt(0)" ::: "memory");
        __builtin_amdgcn_s_barrier();
        __builtin_amdgcn_s_setprio(1);
        mfma_phase(buf, afA, afB);
        __builtin_amdgcn_s_setprio(0);
        asm volatile("s_waitcnt lgkmcnt(0)" ::: "memory");
        __builtin_amdgcn_s_barrier();
        buf ^= 1;
    }
    {   // step 31: nothing issued after -> full drain needed here
        bf16x8 afA, afB;
        agen(1, afA, afB);
        asm volatile("s_waitcnt vmcnt(0) lgkmcnt(0)" ::: "memory");
        __builtin_amdgcn_s_barrier();
        __builtin_amdgcn_s_setprio(1);
        mfma_phase(buf, afA, afB);
        __builtin_amdgcn_s_setprio(0);
    }

    // ---- epilogue: C layout col=lane&15 (d), row=quad*4+r (i) ----
#pragma unroll
    for (int c = 0; c < 2; ++c) {
        int irow = ibase + (2 * ig + c) * 16 + quad * 4;
#pragma unroll
        for (int nt = 0; nt < 4; ++nt) {
            int d = dg * 64 + nt * 16 + m16;
#pragma unroll
            for (int r = 0; r < 4; ++r)
                out[((size_t)b * N_ + irow + r) * D_ + d] = acc[c][nt][r];
        }
    }
}

extern "C" void kernel_launch(void* const* d_in, const int* in_sizes, int n_in,
                              void* d_out, int out_size, void* d_ws, size_t ws_size,
                              hipStream_t stream) {
    const float* x   = (const float*)d_in[0];
    const float* adj = (const float*)d_in[1];
    const float* W   = (const float*)d_in[2];
    const float* be  = (const float*)d_in[3];
    const float* wq  = (const float*)d_in[4];
    const float* bq  = (const float*)d_in[5];
    const float* wk  = (const float*)d_in[6];
    const float* bk  = (const float*)d_in[7];
    float* out = (float*)d_out;

    char* ws = (char*)d_ws;
    size_t off = 0;
    bf16_t* Pb = (bf16_t*)(ws + off); off += (size_t)B_ * D_ * N_ * 2;   // 8 MB
    float* qa  = (float*)(ws + off);  off += (size_t)B_ * N_ * 4;
    float* ka  = (float*)(ws + off);  off += (size_t)B_ * N_ * 4;
    float* denom = (float*)(ws + off); off += (size_t)B_ * N_ * 4;
    float* Eq  = (float*)(ws + off);  off += (size_t)B_ * N_ * 4;
    float* eqs = (float*)(ws + off);  off += (size_t)B_ * N_ * 4;
    float* Ek  = (float*)(ws + off);  off += (size_t)B_ * N_ * 4;
    float* eks = (float*)(ws + off);  off += (size_t)B_ * N_ * 4;
    float* rd  = (float*)(ws + off);  off += (size_t)B_ * N_ * 4;
    float* Eqr = (float*)(ws + off);  off += (size_t)B_ * N_ * 4;
    float* eqr = (float*)(ws + off);  off += (size_t)B_ * N_ * 4;
    unsigned int* bits = (unsigned int*)(ws + off); off += (size_t)N_ * 64 * 4; // 512 KB

    k_pack_adj<<<N_ * N_ / 256, 256, 0, stream>>>(adj, bits);
    k_emb<<<dim3(N_ / 64, B_), 256, 0, stream>>>(x, W, be, wq, bq, wk, bk,
                                                 Pb, qa, ka, Eq, eqs, Ek, eks, denom);
    k_denom<<<dim3(8, 16, 8), 256, 0, stream>>>(bits, qa, ka, Eq, eqs, Ek, eks, denom);
    k_post<<<B_ * N_ / 256, 256, 0, stream>>>(denom, Eq, eqs, rd, Eqr, eqr);
    k_attn<<<512, 256, 0, stream>>>(qa, ka, Ek, eks, rd, Eqr, eqr,
                                    bits, Pb, out);
}

// Round 12
// 180.822 us; speedup vs baseline: 1.2045x; 1.0125x over previous
//
#include <hip/hip_runtime.h>
#include <hip/hip_bf16.h>
#include <stdint.h>

#define B_ 16
#define N_ 2048
#define D_ 128

typedef __bf16 bf16_t;
typedef bf16_t bf16x8 __attribute__((ext_vector_type(8)));
typedef float f32x4 __attribute__((ext_vector_type(4)));

// ---------------- K0: pack adj (fp32 0/1 matrix) into bitmask ----------------
// Grid-strided: 2048 blocks x 256 thr x 8 elems (was 16384 blocks x 1 elem --
// 65536 near-empty waves of dispatch overhead). Same ballot logic, coalesced.
__global__ __launch_bounds__(256) void k_pack_adj(const float* __restrict__ adj,
                                                  unsigned int* __restrict__ bits) {
    int base = blockIdx.x * 256 + threadIdx.x;
#pragma unroll
    for (int it = 0; it < (N_ * N_) / (2048 * 256); ++it) {
        int t = base + it * (2048 * 256);     // over N*N, coalesced per iter
        float v = adj[t];
        unsigned long long m = __ballot(v > 0.5f);
        if ((t & 63) == 0) {
            int i = t >> 11;
            int j = t & 2047;
            bits[i * 64 + (j >> 5)]     = (unsigned int)m;
            bits[i * 64 + (j >> 5) + 1] = (unsigned int)(m >> 32);
        }
    }
}

// ---------------- K1: emb GEMM (64n x 128d tile) + fused q/k + exps ----------
// Pb[b][d][n] = bf16( sum_k x[b][n][k]*W[d][k] + be[d] )   (raw seq_fts, bf16)
// Also zero-inits denom (replaces the memset dispatch).
__global__ __launch_bounds__(256, 2) void k_emb(const float* __restrict__ x,
                                                const float* __restrict__ W,
                                                const float* __restrict__ be,
                                                const float* __restrict__ wq,
                                                const float* __restrict__ bq,
                                                const float* __restrict__ wk,
                                                const float* __restrict__ bk,
                                                bf16_t* __restrict__ Pb,
                                                float* __restrict__ qa, float* __restrict__ ka,
                                                float* __restrict__ Eq, float* __restrict__ eqs,
                                                float* __restrict__ Ek, float* __restrict__ eks,
                                                float* __restrict__ denom) {
    __shared__ float xs[32][68];     // [k][n]  64n + pad
    __shared__ float ws[32][132];    // [k][d]  128d + pad
    __shared__ float qs[64], ks[64];
    int b  = blockIdx.y;
    int n0 = blockIdx.x * 64;
    int tid = threadIdx.x;
    int tx = tid & 15, ty = tid >> 4;   // tx: n-dir (4 n), ty: d-dir (8 d)
    if (tid < 64) { qs[tid] = 0.f; ks[tid] = 0.f; }

    float acc[4][8] = {};               // [n][d]
    f32x4 xr[2], wr[4];

    auto loadregs = [&](int kc) {
#pragma unroll
        for (int s = 0; s < 2; ++s) {
            int p = tid + 256 * s;
            int n = p >> 3, kq = p & 7;
            xr[s] = *(const f32x4*)(x + ((size_t)(b * N_ + n0 + n)) * D_ + kc * 32 + kq * 4);
        }
#pragma unroll
        for (int s = 0; s < 4; ++s) {
            int p = tid + 256 * s;
            int d = p >> 3, kq = p & 7;
            wr[s] = *(const f32x4*)(W + (size_t)d * D_ + kc * 32 + kq * 4);
        }
    };
    auto writelds = [&]() {
#pragma unroll
        for (int s = 0; s < 2; ++s) {
            int p = tid + 256 * s;
            int n = p >> 3, kq = p & 7;
#pragma unroll
            for (int u = 0; u < 4; ++u) xs[kq * 4 + u][n] = xr[s][u];
        }
#pragma unroll
        for (int s = 0; s < 4; ++s) {
            int p = tid + 256 * s;
            int d = p >> 3, kq = p & 7;
#pragma unroll
            for (int u = 0; u < 4; ++u) ws[kq * 4 + u][d] = wr[s][u];
        }
    };

    loadregs(0);
    for (int kc = 0; kc < 4; ++kc) {
        writelds();
        __syncthreads();
        if (kc < 3) loadregs(kc + 1);
#pragma unroll 4
        for (int k = 0; k < 32; ++k) {
            f32x4 xv  = *(const f32x4*)&xs[k][tx * 4];
            f32x4 wv0 = *(const f32x4*)&ws[k][ty * 8];
            f32x4 wv1 = *(const f32x4*)&ws[k][ty * 8 + 4];
#pragma unroll
            for (int i = 0; i < 4; ++i)
#pragma unroll
                for (int j = 0; j < 8; ++j)
                    acc[i][j] += xv[i] * ((j < 4) ? wv0[j] : wv1[j - 4]);
        }
        __syncthreads();
    }

    float qp[4] = {}, kp[4] = {};
#pragma unroll
    for (int j = 0; j < 8; ++j) {
        int d = ty * 8 + j;
        float bj  = be[d];
        float wqj = wq[d];
        float wkj = wk[d];
        f32x4 o;
        bf16_t ob[4];
#pragma unroll
        for (int i = 0; i < 4; ++i) {
            o[i] = acc[i][j] + bj;
            qp[i] += o[i] * wqj;
            kp[i] += o[i] * wkj;
            ob[i] = (bf16_t)o[i];
        }
        *(uint2*)(Pb + ((size_t)b * D_ + d) * N_ + n0 + tx * 4) = *(uint2*)ob;
    }
#pragma unroll
    for (int i = 0; i < 4; ++i) {
        atomicAdd(&qs[tx * 4 + i], qp[i]);
        atomicAdd(&ks[tx * 4 + i], kp[i]);
    }
    __syncthreads();
    if (tid < 64) {
        int idx = b * N_ + n0 + tid;
        float aq = qs[tid] + bq[0];
        float ak = ks[tid] + bk[0];
        qa[idx] = aq;          ka[idx] = ak;
        Eq[idx] = expf(aq);    eqs[idx] = expf(0.01f * aq);
        Ek[idx] = expf(ak);    eks[idx] = expf(0.01f * ak);
        denom[idx] = 0.f;      // replaces hipMemsetAsync (k_denom runs after)
    }
}

// ---------------- K2: denom[b][j] = sum_i V(b,i,j) ---------------------------
__global__ __launch_bounds__(256) void k_denom(const unsigned int* __restrict__ bits,
                                               const float* __restrict__ qa,
                                               const float* __restrict__ ka,
                                               const float* __restrict__ Eq,
                                               const float* __restrict__ eqs,
                                               const float* __restrict__ Ek,
                                               const float* __restrict__ eks,
                                               float* __restrict__ denom) {
    int jt  = blockIdx.x;     // 0..7
    int b   = blockIdx.y;     // 0..15
    int seg = blockIdx.z;     // 0..7
    int j = jt * 256 + threadIdx.x;
    float qj  = qa[b * N_ + j];
    float Eqj = Eq[b * N_ + j];
    float eqj = eqs[b * N_ + j];
    int shift = j & 31;
    int wid   = j >> 5;
    float acc = 0.f;
    int i0 = seg * 256;
#pragma unroll 16
    for (int i = i0; i < i0 + 256; ++i) {
        float kk  = ka[b * N_ + i];
        float Ekk = Ek[b * N_ + i];
        float ekk = eks[b * N_ + i];
        unsigned int w = bits[i * 64 + wid];
        float z  = kk + qj;
        float f1 = z > 0.f ? Ekk : ekk;
        float f2 = z > 0.f ? Eqj : eqj;
        float v  = f1 * f2;
        acc += ((w >> shift) & 1u) ? v : 1.0f;
    }
    atomicAdd(&denom[b * N_ + j], acc);
}

// ---------------- K2b: rd = 1/denom; Eqr = Eq*rd; eqr = eqs*rd ---------------
__global__ __launch_bounds__(256) void k_post(const float* __restrict__ denom,
                                              const float* __restrict__ Eq,
                                              const float* __restrict__ eqs,
                                              float* __restrict__ rd,
                                              float* __restrict__ Eqr,
                                              float* __restrict__ eqr) {
    int t = blockIdx.x * 256 + threadIdx.x;   // over B*N
    float r = 1.0f / denom[t];
    rd[t]  = r;
    Eqr[t] = Eq[t] * r;
    eqr[t] = eqs[t] * r;
}

// ---------------- K3: vals = A' @ P ------------------------------------------
// A'[i,j] = edge ? (z>0?Ek_i:ek_i)*(z>0?Eqr_j:eqr_j) : rd_j   (5 VALU/elem)
// SESSION-BEST CONFIGURATION (measured 45.5-49 us k_attn / 183.0 us total,
// R4+R11): 64i x 128d tile, 64-j step, counted-vmcnt pipeline (vmcnt(14),
// lgkm-only barrier2), A-exchange via ldsA, XCD-AWARE DECODE (FETCH 35->6.7
// MB), setprio(1) around MFMA.
// Verified local optimum: R1/R3 (more blocks), R5 (rcp fusion), R7 (BK=128),
// R8 (self-sufficient waves), R9 (single barrier), R10 (agen pipeline) all
// regressed 10-65%. Latency-bound at 2 lockstep blocks/CU. DO NOT MODIFY.
__global__ __launch_bounds__(256, 2) void k_attn(const float* __restrict__ qa,
                                                 const float* __restrict__ ka,
                                                 const float* __restrict__ Ek,
                                                 const float* __restrict__ eks,
                                                 const float* __restrict__ rd,
                                                 const float* __restrict__ Eqr,
                                                 const float* __restrict__ eqr,
                                                 const unsigned int* __restrict__ bits,
                                                 const bf16_t* __restrict__ Pb,
                                                 float* __restrict__ out) {
    __shared__ __align__(16) bf16_t ldsB[2][128 * 64];    // 32 KB, B dbuf
    __shared__ __align__(16) bf16_t ldsA[4 * 2 * 64 * 8]; // 8 KB, A exchange
    int n     = blockIdx.x;        // 0..511
    int xcd   = n & 7;             // HW round-robin: block n -> XCD n%8
    int slot  = n >> 3;            // 0..63 within this XCD
    int b     = xcd * 2 + (slot >> 5);   // XCD owns 2 batches
    int ibase = (slot & 31) * 64;        // walk i-tiles for fixed b
    int tid   = threadIdx.x;
    int w     = tid >> 6;          // 0..3
    int lane  = tid & 63;
    int m16   = lane & 15;
    int quad  = lane >> 4;
    int ig    = w & 1;             // i-group (32 i)
    int dg    = w >> 1;            // d-group (64 d); also my j-half hh

    int iA = ibase + (2 * ig) * 16 + m16;
    int iB = iA + 16;
    float mkR0 = -ka[b * N_ + iA], mkR1 = -ka[b * N_ + iB];   // z>0 <=> q_j > -k_i
    float EkR0 = Ek[b * N_ + iA],  EkR1 = Ek[b * N_ + iB];
    float ekR0 = eks[b * N_ + iA], ekR1 = eks[b * N_ + iB];
    const unsigned int* brA = bits + (size_t)iA * 64;
    const unsigned int* brB = bits + (size_t)iB * 64;
    const float* qp  = qa  + b * N_;
    const float* Erp = Eqr + b * N_;
    const float* erp = eqr + b * N_;
    const float* rdp = rd  + b * N_;
    const bf16_t* PtB = Pb + (size_t)b * D_ * N_;

    f32x4 acc[2][4];   // [i-chunk][d-tile]
#pragma unroll
    for (int c = 0; c < 2; ++c)
#pragma unroll
        for (int nt = 0; nt < 4; ++nt) acc[c][nt] = (f32x4){0.f, 0.f, 0.f, 0.f};

    // ---- pipeline registers (parity-indexed; compile-time after unroll) ----
    f32x4 qv4[2][2], Er4[2][2], er4[2][2], rd4[2][2];  // [par][half4] (own hh only)
    unsigned int mA[2], mB[2];

    auto ldj = [&](int par, int jb) {
        int j0 = jb + dg * 32 + quad * 8;
        qv4[par][0] = *(const f32x4*)(qp  + j0);
        qv4[par][1] = *(const f32x4*)(qp  + j0 + 4);
        Er4[par][0] = *(const f32x4*)(Erp + j0);
        Er4[par][1] = *(const f32x4*)(Erp + j0 + 4);
        er4[par][0] = *(const f32x4*)(erp + j0);
        er4[par][1] = *(const f32x4*)(erp + j0 + 4);
        rd4[par][0] = *(const f32x4*)(rdp + j0);
        rd4[par][1] = *(const f32x4*)(rdp + j0 + 4);
        mA[par] = brA[(jb >> 5) + dg];
        mB[par] = brB[(jb >> 5) + dg];
    };

    // Stage 128d x 64j bf16 tile (16 KB), XOR swizzle on the GLOBAL address.
    auto stage = [&](int bufi, int jb) {
#pragma unroll
        for (int t = 0; t < 4; ++t) {
            int off = t * 4096 + tid * 16;               // byte offset in tile
            int d   = off >> 7;                          // row (128 B = 64 j)
            int g   = ((off & 127) >> 4) ^ (d & 7);      // swizzled j-chunk
            const bf16_t* gp = PtB + (size_t)d * N_ + jb + g * 8;
            __builtin_amdgcn_global_load_lds(
                (const __attribute__((address_space(1))) void*)gp,
                (__attribute__((address_space(3))) void*)((char*)(&ldsB[bufi][0]) + off),
                16, 0, 0);
        }
    };

    // ---- A-gen: own hh only, both i-chunks, from registers; publish to ldsA.
    auto agen = [&](int par, bf16x8& afA, bf16x8& afB) {
#pragma unroll
        for (int t = 0; t < 8; ++t) {
            float qv = (t < 4) ? qv4[par][0][t] : qv4[par][1][t - 4];
            float Er = (t < 4) ? Er4[par][0][t] : Er4[par][1][t - 4];
            float er = (t < 4) ? er4[par][0][t] : er4[par][1][t - 4];
            float rj = (t < 4) ? rd4[par][0][t] : rd4[par][1][t - 4];
            int bit = quad * 8 + t;
            {
                bool c = qv > mkR0;
                float v = (c ? EkR0 : ekR0) * (c ? Er : er);
                afA[t] = (bf16_t)(((mA[par] >> bit) & 1u) ? v : rj);
            }
            {
                bool c = qv > mkR1;
                float v = (c ? EkR1 : ekR1) * (c ? Er : er);
                afB[t] = (bf16_t)(((mB[par] >> bit) & 1u) ? v : rj);
            }
        }
        *(bf16x8*)((char*)ldsA + ((((2 * ig + 0) * 2 + dg) * 64 + lane) * 16)) = afA;
        *(bf16x8*)((char*)ldsA + ((((2 * ig + 1) * 2 + dg) * 64 + lane) * 16)) = afB;
    };

    // ---- MFMA: own hh from regs, other hh from ldsA ----
    auto mfma_phase = [&](int buf, const bf16x8& afA, const bf16x8& afB) {
        {
            int cph = ((dg * 4 + quad) ^ (m16 & 7)) * 8;
#pragma unroll
            for (int nt = 0; nt < 4; ++nt) {
                int d = dg * 64 + nt * 16 + m16;
                bf16x8 bf = *(const bf16x8*)&ldsB[buf][d * 64 + cph];
                acc[0][nt] = __builtin_amdgcn_mfma_f32_16x16x32_bf16(afA, bf, acc[0][nt], 0, 0, 0);
                acc[1][nt] = __builtin_amdgcn_mfma_f32_16x16x32_bf16(afB, bf, acc[1][nt], 0, 0, 0);
            }
        }
        {
            int oh = 1 - dg;
            bf16x8 a0 = *(const bf16x8*)((char*)ldsA + ((((2 * ig + 0) * 2 + oh) * 64 + lane) * 16));
            bf16x8 a1 = *(const bf16x8*)((char*)ldsA + ((((2 * ig + 1) * 2 + oh) * 64 + lane) * 16));
            int cph = ((oh * 4 + quad) ^ (m16 & 7)) * 8;
#pragma unroll
            for (int nt = 0; nt < 4; ++nt) {
                int d = dg * 64 + nt * 16 + m16;
                bf16x8 bf = *(const bf16x8*)&ldsB[buf][d * 64 + cph];
                acc[0][nt] = __builtin_amdgcn_mfma_f32_16x16x32_bf16(a0, bf, acc[0][nt], 0, 0, 0);
                acc[1][nt] = __builtin_amdgcn_mfma_f32_16x16x32_bf16(a1, bf, acc[1][nt], 0, 0, 0);
            }
        }
    };

    stage(0, 0);
    ldj(0, 0);
    // no startup drain: barrier1 of step 0 (vmcnt(14)) covers the initial stage
    int buf = 0;
#pragma unroll 1
    for (int s2 = 0; s2 < 15; ++s2) {          // steps 0..29
#pragma unroll
        for (int par = 0; par < 2; ++par) {
            int jb = (s2 * 2 + par) * 64;
            ldj(par ^ 1, jb + 64);             // j-side regs for next step
            stage(buf ^ 1, jb + 64);           // B prefetch for next step

            bf16x8 afA, afB;
            agen(par, afA, afB);
            // this step's 14 loads were issued one step ago; the 14 just
            // issued stay in flight across the barrier
            asm volatile("s_waitcnt vmcnt(14) lgkmcnt(0)" ::: "memory");
            __builtin_amdgcn_s_barrier();

            __builtin_amdgcn_s_setprio(1);
            mfma_phase(buf, afA, afB);
            __builtin_amdgcn_s_setprio(0);

            asm volatile("s_waitcnt lgkmcnt(0)" ::: "memory");
            __builtin_amdgcn_s_barrier();
            buf ^= 1;
        }
    }
    {   // step 30: still prefetches step 31
        ldj(1, 31 * 64);
        stage(buf ^ 1, 31 * 64);
        bf16x8 afA, afB;
        agen(0, afA, afB);
        asm volatile("s_waitcnt vmcnt(14) lgkmcnt(0)" ::: "memory");
        __builtin_amdgcn_s_barrier();
        __builtin_amdgcn_s_setprio(1);
        mfma_phase(buf, afA, afB);
        __builtin_amdgcn_s_setprio(0);
        asm volatile("s_waitcnt lgkmcnt(0)" ::: "memory");
        __builtin_amdgcn_s_barrier();
        buf ^= 1;
    }
    {   // step 31: nothing issued after -> full drain needed here
        bf16x8 afA, afB;
        agen(1, afA, afB);
        asm volatile("s_waitcnt vmcnt(0) lgkmcnt(0)" ::: "memory");
        __builtin_amdgcn_s_barrier();
        __builtin_amdgcn_s_setprio(1);
        mfma_phase(buf, afA, afB);
        __builtin_amdgcn_s_setprio(0);
    }

    // ---- epilogue: C layout col=lane&15 (d), row=quad*4+r (i) ----
#pragma unroll
    for (int c = 0; c < 2; ++c) {
        int irow = ibase + (2 * ig + c) * 16 + quad * 4;
#pragma unroll
        for (int nt = 0; nt < 4; ++nt) {
            int d = dg * 64 + nt * 16 + m16;
#pragma unroll
            for (int r = 0; r < 4; ++r)
                out[((size_t)b * N_ + irow + r) * D_ + d] = acc[c][nt][r];
        }
    }
}

extern "C" void kernel_launch(void* const* d_in, const int* in_sizes, int n_in,
                              void* d_out, int out_size, void* d_ws, size_t ws_size,
                              hipStream_t stream) {
    const float* x   = (const float*)d_in[0];
    const float* adj = (const float*)d_in[1];
    const float* W   = (const float*)d_in[2];
    const float* be  = (const float*)d_in[3];
    const float* wq  = (const float*)d_in[4];
    const float* bq  = (const float*)d_in[5];
    const float* wk  = (const float*)d_in[6];
    const float* bk  = (const float*)d_in[7];
    float* out = (float*)d_out;

    char* ws = (char*)d_ws;
    size_t off = 0;
    bf16_t* Pb = (bf16_t*)(ws + off); off += (size_t)B_ * D_ * N_ * 2;   // 8 MB
    float* qa  = (float*)(ws + off);  off += (size_t)B_ * N_ * 4;
    float* ka  = (float*)(ws + off);  off += (size_t)B_ * N_ * 4;
    float* denom = (float*)(ws + off); off += (size_t)B_ * N_ * 4;
    float* Eq  = (float*)(ws + off);  off += (size_t)B_ * N_ * 4;
    float* eqs = (float*)(ws + off);  off += (size_t)B_ * N_ * 4;
    float* Ek  = (float*)(ws + off);  off += (size_t)B_ * N_ * 4;
    float* eks = (float*)(ws + off);  off += (size_t)B_ * N_ * 4;
    float* rd  = (float*)(ws + off);  off += (size_t)B_ * N_ * 4;
    float* Eqr = (float*)(ws + off);  off += (size_t)B_ * N_ * 4;
    float* eqr = (float*)(ws + off);  off += (size_t)B_ * N_ * 4;
    unsigned int* bits = (unsigned int*)(ws + off); off += (size_t)N_ * 64 * 4; // 512 KB

    k_pack_adj<<<2048, 256, 0, stream>>>(adj, bits);
    k_emb<<<dim3(N_ / 64, B_), 256, 0, stream>>>(x, W, be, wq, bq, wk, bk,
                                                 Pb, qa, ka, Eq, eqs, Ek, eks, denom);
    k_denom<<<dim3(8, 16, 8), 256, 0, stream>>>(bits, qa, ka, Eq, eqs, Ek, eks, denom);
    k_post<<<B_ * N_ / 256, 256, 0, stream>>>(denom, Eq, eqs, rd, Eqr, eqr);
    k_attn<<<512, 256, 0, stream>>>(qa, ka, Ek, eks, rd, Eqr, eqr,
                                    bits, Pb, out);
}